// Round 7
// baseline (2496.774 us; speedup 1.0000x reference)
//
#include <hip/hip_runtime.h>
#include <math.h>

#define B_   16
#define N_   2048
#define G_   128
#define K_   32
#define D_   384
#define L_   12
#define H_   6
#define DH_  64
#define DFF_ 1536
#define S_   130
#define NP_  50
#define NC_  16
#define LD_  64

typedef __attribute__((ext_vector_type(8))) short bf16x8;
typedef __attribute__((ext_vector_type(4))) float f32x4;

// ---------------------------------------------------------------- utilities
__device__ __forceinline__ float gelu_f(float x) {
    float u = 0.7978845608028654f * (x + 0.044715f * x * x * x);
    float t = 1.f - 2.f / (1.f + __expf(2.f * u));   // tanh(u)
    return 0.5f * x * (1.f + t);
}

__device__ __forceinline__ void split1(float a, unsigned short& hi, unsigned short& lo) {
    unsigned u = __float_as_uint(a);
    unsigned r = (u + 0x7fffu + ((u >> 16) & 1u)) & 0xffff0000u;
    hi = (unsigned short)(r >> 16);
    float al = a - __uint_as_float(r);
    unsigned u2 = __float_as_uint(al);
    lo = (unsigned short)((u2 + 0x7fffu + ((u2 >> 16) & 1u)) >> 16);
}

__device__ __forceinline__ void split8(const float* v, bf16x8& hi, bf16x8& lo) {
#pragma unroll
    for (int e = 0; e < 8; e++) {
        unsigned short h, l;
        split1(v[e], h, l);
        hi[e] = (short)h; lo[e] = (short)l;
    }
}

#define LMIN(da, pa, db, pb) { bool s_ = ((db) < (da)) || ((db) == (da) && (pb) < (pa)); \
                               (da) = s_ ? (db) : (da); (pa) = s_ ? (pb) : (pa); }

// ---------------------------------------------------------------- KNN: 4 waves x 512 pts local top-32, rank-merge
__global__ __launch_bounds__(256) void knn_kernel(const float* __restrict__ xyz, int* __restrict__ idx) {
    int bg = blockIdx.x;
    int b = bg >> 7, g = bg & 127;
    int t = threadIdx.x, w = t >> 6, lane = t & 63;
    const float* xb = xyz + (size_t)b * N_ * 3;
    float cx = xb[(g * 16) * 3 + 0], cy = xb[(g * 16) * 3 + 1], cz = xb[(g * 16) * 3 + 2];
    float d[8];
#pragma unroll
    for (int i = 0; i < 8; i++) {
        int p = w * 512 + i * 64 + lane;
        float dx = xb[p * 3 + 0] - cx, dy = xb[p * 3 + 1] - cy, dz = xb[p * 3 + 2] - cz;
        d[i] = dx * dx + dy * dy + dz * dz;
    }
    __shared__ float cd[128];
    __shared__ int   cpi[128];
    for (int r = 0; r < K_; r++) {
        float td[4]; int tp[4];
#pragma unroll
        for (int i = 0; i < 4; i++) {            // merge reg i with i+4 (index order preserved on tie)
            bool s = d[i + 4] < d[i];
            td[i] = s ? d[i + 4] : d[i];
            tp[i] = (s ? (i + 4) : i) * 64 + lane;
        }
        LMIN(td[0], tp[0], td[2], tp[2]);
        LMIN(td[1], tp[1], td[3], tp[3]);
        LMIN(td[0], tp[0], td[1], tp[1]);
        float bd = td[0]; int bp = tp[0];
#pragma unroll
        for (int off = 1; off < 64; off <<= 1) {
            float od = __shfl_xor(bd, off); int oq = __shfl_xor(bp, off);
            LMIN(bd, bp, od, oq);
        }
        if (lane == 0) { cd[w * 32 + r] = bd; cpi[w * 32 + r] = w * 512 + bp; }
        bool mine = ((bp & 63) == lane);
        int ki = bp >> 6;
#pragma unroll
        for (int i = 0; i < 8; i++) d[i] = (mine && ki == i) ? 1e38f : d[i];
    }
    __syncthreads();
    if (w == 0) {
        float a0 = cd[2 * lane], a1 = cd[2 * lane + 1];
        int p0 = cpi[2 * lane], p1 = cpi[2 * lane + 1];
        int r0 = 0, r1 = 0;
        for (int j = 0; j < 128; j++) {
            float dj = cd[j]; int pj = cpi[j];
            r0 += (dj < a0) || (dj == a0 && pj < p0);
            r1 += (dj < a1) || (dj == a1 && pj < p1);
        }
        int* op = idx + (size_t)bg * K_;
        if (r0 < K_) op[r0] = p0;
        if (r1 < K_) op[r1] = p1;
    }
}

// ---------------------------------------------------------------- group PointNet -> tokens (B,G,D)
__global__ __launch_bounds__(128) void tokens_kernel(const float* __restrict__ xyz, const int* __restrict__ idx,
                                                     const float* __restrict__ We1, const float* __restrict__ be1,
                                                     const float* __restrict__ We2, const float* __restrict__ be2,
                                                     float* __restrict__ tokens) {
    int bg = blockIdx.x;
    int b = bg >> 7, g = bg & 127;
    int t = threadIdx.x;
    __shared__ float rel[32][3];
    __shared__ float maxh[128];
    const float* xb = xyz + (size_t)b * N_ * 3;
    if (t < 32) {
        int p = idx[(size_t)bg * K_ + t];
        rel[t][0] = xb[p * 3 + 0] - xb[g * 16 * 3 + 0];
        rel[t][1] = xb[p * 3 + 1] - xb[g * 16 * 3 + 1];
        rel[t][2] = xb[p * 3 + 2] - xb[g * 16 * 3 + 2];
    }
    __syncthreads();
    float w0 = We1[t], w1 = We1[128 + t], w2 = We1[256 + t], bb = be1[t];
    float mx = -1e38f;
#pragma unroll 8
    for (int k = 0; k < 32; k++) {
        float v = rel[k][0] * w0 + rel[k][1] * w1 + rel[k][2] * w2 + bb;
        v = fmaxf(v, 0.f);
        mx = fmaxf(mx, v);
    }
    maxh[t] = mx;
    __syncthreads();
    float* tok = tokens + (size_t)bg * D_;
    for (int jj = t; jj < D_; jj += 128) {
        float acc = be2[jj];
        for (int c = 0; c < 128; c++) acc += maxh[c] * We2[c * D_ + jj];
        tok[jj] = acc;
    }
}

// ---------------------------------------------------------------- x = seq + type_emb + pos  (B,S,D)
__global__ __launch_bounds__(128) void buildx_kernel(const float* __restrict__ xyz, const float* __restrict__ tokens,
                                                     const float* __restrict__ Wp1, const float* __restrict__ bp1,
                                                     const float* __restrict__ Wp2, const float* __restrict__ bp2,
                                                     const float* __restrict__ bos, const float* __restrict__ eos,
                                                     const float* __restrict__ te, float* __restrict__ x) {
    int bs = blockIdx.x;
    int b = bs / S_, s = bs % S_;
    int t = threadIdx.x;
    __shared__ float h1[128];
    float c0 = 0.f, c1 = 0.f, c2 = 0.f;
    if (s >= 1 && s <= G_) {
        const float* xb = xyz + ((size_t)b * N_ + (size_t)(s - 1) * 16) * 3;
        c0 = xb[0]; c1 = xb[1]; c2 = xb[2];
    }
    h1[t] = fmaxf(c0 * Wp1[t] + c1 * Wp1[128 + t] + c2 * Wp1[256 + t] + bp1[t], 0.f);
    __syncthreads();
    int tid = (s == 0) ? 0 : ((s == S_ - 1) ? 2 : 1);
    float* xr = x + (size_t)bs * D_;
    for (int jj = t; jj < D_; jj += 128) {
        float acc = bp2[jj];
        for (int c = 0; c < 128; c++) acc += h1[c] * Wp2[c * D_ + jj];
        float base = (s == 0) ? bos[jj] : (s == S_ - 1 ? eos[jj] : tokens[((size_t)b * G_ + (s - 1)) * D_ + jj]);
        xr[jj] = base + te[tid * D_ + jj] + acc;
    }
}

// ---------------------------------------------------------------- LayerNorm (+ partial-sum reduce + pack)
__global__ __launch_bounds__(256) void ln_kernel(
    const float* __restrict__ xin, float* __restrict__ xout,
    const float* __restrict__ P0, const float* __restrict__ P1,
    const float* __restrict__ P2, const float* __restrict__ P3,
    const float* __restrict__ addb,
    const float* __restrict__ g, const float* __restrict__ b,
    unsigned short* __restrict__ pout, float* __restrict__ fout, int rows) {
    int r = blockIdx.x * 4 + (threadIdx.x >> 6);
    if (r >= rows) return;
    int lane = threadIdx.x & 63;
    const float* xr = xin + (size_t)r * 384;
    float v[6]; float s = 0.f, s2 = 0.f;
#pragma unroll
    for (int i = 0; i < 6; i++) {
        int c = lane + 64 * i;
        float t = xr[c];
        size_t o = (size_t)r * 384 + c;
        if (P0) t += P0[o] + P1[o];
        if (P2) t += P2[o] + P3[o];
        if (addb) t += addb[c];
        if (xout) xout[o] = t;
        v[i] = t; s += t; s2 += t * t;
    }
#pragma unroll
    for (int off = 1; off < 64; off <<= 1) { s += __shfl_xor(s, off); s2 += __shfl_xor(s2, off); }
    float m = s * (1.f / 384.f);
    float var = s2 * (1.f / 384.f) - m * m;
    float rstd = 1.0f / sqrtf(var + 1e-5f);
    int rl = r & 15, mfo = r >> 4;
#pragma unroll
    for (int i = 0; i < 6; i++) {
        int c = lane + 64 * i;
        float y = (v[i] - m) * rstd * g[c] + b[c];
        if (fout) fout[(size_t)r * 384 + c] = y;
        if (pout) {
            unsigned short hi, lo;
            split1(y, hi, lo);
            size_t ix = (((size_t)mfo * 12 + (c >> 5)) * 64 + rl + ((c >> 3) & 3) * 16) * 8 + (c & 7);
            pout[ix] = hi;
            pout[ix + 798720] = lo;
        }
    }
}

// ---------------------------------------------------------------- pack ALL weights in one launch
__global__ __launch_bounds__(256) void packall_kernel(
    const float* __restrict__ Wqkv, const float* __restrict__ Wo, const float* __restrict__ Wf1,
    const float* __restrict__ Wf2, const float* __restrict__ Wc1, const float* __restrict__ Wc2,
    const float* __restrict__ Wc3,
    unsigned short* __restrict__ qkvP, unsigned short* __restrict__ woP, unsigned short* __restrict__ f1P,
    unsigned short* __restrict__ f2P, unsigned short* __restrict__ wc1P, unsigned short* __restrict__ wc2P,
    unsigned short* __restrict__ wc3P) {
    int id = blockIdx.x;
    const float* src; unsigned short* dst; int Ksz, Nsz, nftot, kb, nxb, loc;
    if (id < 2592)       { loc = id;         src = Wqkv; dst = qkvP; Ksz = 384;  Nsz = 1152; nftot = 72; kb = 12; nxb = 18; }
    else if (id < 3456)  { loc = id - 2592;  src = Wo;   dst = woP;  Ksz = 384;  Nsz = 384;  nftot = 24; kb = 12; nxb = 6;  }
    else if (id < 6912)  { loc = id - 3456;  src = Wf1;  dst = f1P;  Ksz = 384;  Nsz = 1536; nftot = 96; kb = 12; nxb = 24; }
    else if (id < 10368) { loc = id - 6912;  src = Wf2;  dst = f2P;  Ksz = 1536; Nsz = 384;  nftot = 24; kb = 48; nxb = 6;  }
    else if (id < 10464) { loc = id - 10368; src = Wc1;  dst = wc1P; Ksz = 384;  Nsz = 512;  nftot = 32; kb = 12; nxb = 8;  }
    else if (id < 10528) { loc = id - 10464; src = Wc2;  dst = wc2P; Ksz = 512;  Nsz = 256;  nftot = 16; kb = 16; nxb = 4;  }
    else                 { loc = id - 10528; src = Wc3;  dst = wc3P; Ksz = 256;  Nsz = 50;   nftot = 4;  kb = 8;  nxb = 1;  }
    int xb = loc % nxb; int rest = loc / nxb; int kblk = rest % kb; int l = rest / kb;
    src += (size_t)l * Ksz * Nsz;
    dst += (size_t)l * 2 * nftot * kb * 512;
    int nf = xb * 4 + (threadIdx.x >> 6);
    if (nf >= nftot) return;
    int lane = threadIdx.x & 63;
    int n = nf * 16 + (lane & 15);
    int k0 = kblk * 32 + (lane >> 4) * 8;
    float av[8];
#pragma unroll
    for (int j = 0; j < 8; j++)
        av[j] = (n < Nsz) ? src[(size_t)(k0 + j) * Nsz + n] : 0.f;
    bf16x8 hi, lo;
    split8(av, hi, lo);
    size_t slot = ((size_t)nf * kb + kblk) * 512 + lane * 8;
    *(bf16x8*)(dst + slot) = hi;
    *(bf16x8*)(dst + slot + (size_t)nftot * kb * 512) = lo;
}

// ---------------------------------------------------------------- packed-A × packed-B MFMA GEMM
template<int MF, int NF, int WNS, int ACT, int FRAGOUT>
__global__ __launch_bounds__(WNS * 64) void gemm_pk(
    const unsigned short* __restrict__ Ap, const unsigned short* __restrict__ Bp,
    int mftot, int nftot, int kbt, int kbc,
    const float* __restrict__ bias, const float* __restrict__ bng, const float* __restrict__ bnb,
    float* __restrict__ C, unsigned short* __restrict__ Cp, size_t CploS, int ckbt,
    int M, int N) {
    int w = threadIdx.x >> 6, lane = threadIdx.x & 63;
    int mf0 = blockIdx.y * MF;
    int nf0 = (blockIdx.x * WNS + w) * NF;
    int k0 = blockIdx.z * kbc;
    f32x4 acc[MF][NF];
#pragma unroll
    for (int i = 0; i < MF; i++)
#pragma unroll
        for (int j = 0; j < NF; j++) acc[i][j] = (f32x4){0.f, 0.f, 0.f, 0.f};
    const size_t AloS = (size_t)mftot * kbt * 512, BloS = (size_t)nftot * kbt * 512;
    const unsigned short* Ab = Ap + ((size_t)mf0 * kbt + k0) * 512 + lane * 8;
    const unsigned short* Bb = Bp + ((size_t)nf0 * kbt + k0) * 512 + lane * 8;
#pragma unroll 2
    for (int kk = 0; kk < kbc; kk++) {
        bf16x8 ah[MF], al[MF], bh[NF], bl[NF];
#pragma unroll
        for (int i = 0; i < MF; i++) {
            const unsigned short* p = Ab + ((size_t)i * kbt + kk) * 512;
            ah[i] = *(const bf16x8*)p;
            al[i] = *(const bf16x8*)(p + AloS);
        }
#pragma unroll
        for (int j = 0; j < NF; j++) {
            const unsigned short* p = Bb + ((size_t)j * kbt + kk) * 512;
            bh[j] = *(const bf16x8*)p;
            bl[j] = *(const bf16x8*)(p + BloS);
        }
#pragma unroll
        for (int j = 0; j < NF; j++)
#pragma unroll
            for (int i = 0; i < MF; i++) {
                acc[i][j] = __builtin_amdgcn_mfma_f32_16x16x32_bf16(ah[i], bh[j], acc[i][j], 0, 0, 0);
                acc[i][j] = __builtin_amdgcn_mfma_f32_16x16x32_bf16(al[i], bh[j], acc[i][j], 0, 0, 0);
                acc[i][j] = __builtin_amdgcn_mfma_f32_16x16x32_bf16(ah[i], bl[j], acc[i][j], 0, 0, 0);
            }
    }
    int lm = lane & 15, lg = lane >> 4;
    const float rsq = 1.0f / sqrtf(1.0f + 1e-5f);
    float* Cz = C ? (C + (size_t)blockIdx.z * ((size_t)M * N)) : nullptr;
#pragma unroll
    for (int i = 0; i < MF; i++) {
#pragma unroll
        for (int r = 0; r < 4; r++) {
            int row = (mf0 + i) * 16 + lg * 4 + r;
#pragma unroll
            for (int j = 0; j < NF; j++) {
                int col = (nf0 + j) * 16 + lm;
                float v = acc[i][j][r];
                if (bias) v += bias[col];
                if (ACT == 2) v = gelu_f(v);
                else if (ACT == 3) v = fmaxf(bng[col] * v * rsq + bnb[col], 0.f);
                if (FRAGOUT) {
                    unsigned short hi, lo;
                    split1(v, hi, lo);
                    size_t ix = (((size_t)(mf0 + i) * ckbt + (col >> 5)) * 64 + (row & 15) + ((col >> 3) & 3) * 16) * 8 + (col & 7);
                    Cp[ix] = hi;
                    Cp[ix + CploS] = lo;
                } else if (col < N) {
                    Cz[(size_t)row * N + col] = v;
                }
            }
        }
    }
}

// ---------------------------------------------------------------- fused attention: K-only LDS, V from L2, 8 q-chunks
__global__ __launch_bounds__(256) void attn_kernel(const float* __restrict__ Q0, const float* __restrict__ Q1,
                                                   const float* __restrict__ bq,
                                                   unsigned short* __restrict__ outP, float* __restrict__ outF) {
    __shared__ float Ksh[S_ * 65];
    __shared__ float att[4][132];
    int blk = blockIdx.x;
    int bh = blk >> 3, qc = blk & 7;
    int b = bh / H_, h = bh % H_;
    int t = threadIdx.x, w = t >> 6, lane = t & 63;
    const size_t base = (size_t)b * S_ * 1152;
    float kbias = bq ? bq[384 + h * 64 + (t & 63)] : 0.f;   // d = e&63 is constant across staging loop
    for (int e = t; e < S_ * 64; e += 256) {
        int k = e >> 6, d = e & 63;
        size_t ok = base + (size_t)k * 1152 + 384 + h * 64 + d;
        float kv = Q0[ok];
        if (Q1) kv += Q1[ok];
        Ksh[k * 65 + d] = kv + kbias;
    }
    __syncthreads();
    int q0 = qc * 17;
    int qend = q0 + 17; if (qend > S_) qend = S_;
    int r2 = (lane < 2) ? (128 + lane) : 0;
    float qb = bq ? bq[h * 64 + lane] : 0.f;
    float vb = bq ? bq[768 + h * 64 + lane] : 0.f;          // softmax weights sum to 1 -> V bias hoists out
    const float* v0 = Q0 + base + 768 + h * 64 + lane;
    const float* v1 = Q1 ? (Q1 + base + 768 + h * 64 + lane) : nullptr;
    for (int q = q0 + w; q < qend; q += 4) {
        size_t oq = base + (size_t)q * 1152 + h * 64 + lane;
        float qv = Q0[oq];
        if (Q1) qv += Q1[oq];
        qv += qb;
        float s0 = 0.f, s1 = 0.f, s2 = 0.f;
#pragma unroll 16
        for (int d = 0; d < 64; d++) {
            float qd = __shfl(qv, d);
            s0 += qd * Ksh[lane * 65 + d];
            s1 += qd * Ksh[(lane + 64) * 65 + d];
            s2 += qd * Ksh[r2 * 65 + d];
        }
        s0 *= 0.125f; s1 *= 0.125f; s2 *= 0.125f;
        float m = fmaxf(s0, s1);
        if (lane < 2) m = fmaxf(m, s2);
        for (int off = 1; off < 64; off <<= 1) m = fmaxf(m, __shfl_xor(m, off));
        float e0 = __expf(s0 - m), e1 = __expf(s1 - m);
        float e2 = (lane < 2) ? __expf(s2 - m) : 0.f;
        float l = e0 + e1 + e2;
        for (int off = 1; off < 64; off <<= 1) l += __shfl_xor(l, off);
        float inv = 1.f / l;
        att[w][lane] = e0 * inv;
        att[w][lane + 64] = e1 * inv;
        if (lane < 2) att[w][lane + 128] = e2 * inv;
        float acc = 0.f;
        if (v1) {
#pragma unroll 5
            for (int k = 0; k < S_; k++) acc += att[w][k] * (v0[(size_t)k * 1152] + v1[(size_t)k * 1152]);
        } else {
#pragma unroll 5
            for (int k = 0; k < S_; k++) acc += att[w][k] * v0[(size_t)k * 1152];
        }
        acc += vb;
        int row = b * S_ + q;
        if (outP) {
            unsigned short hi, lo;
            split1(acc, hi, lo);
            size_t ix = (((size_t)(row >> 4) * 12 + (h * 2 + (lane >> 5))) * 64 + (row & 15) + ((lane >> 3) & 3) * 16) * 8 + (lane & 7);
            outP[ix] = hi;
            outP[ix + 798720] = lo;
        } else {
            outF[(size_t)row * D_ + h * 64 + lane] = acc;
        }
    }
}

// ---------------------------------------------------------------- fused: global max over patches -> head base vector
__global__ __launch_bounds__(512) void gmaxbase_kernel(const float* __restrict__ hh, const int* __restrict__ cls,
                                                       const float* __restrict__ Wl, const float* __restrict__ bl,
                                                       const float* __restrict__ Wc1, const float* __restrict__ bc1,
                                                       float* __restrict__ baseb) {
    int b = blockIdx.x;
    int t = threadIdx.x;
    __shared__ float gm[384];
    __shared__ float clsf[64];
    if (t < 384) {
        float m = -1e38f;
        for (int g = 0; g < G_; g++) m = fmaxf(m, hh[((size_t)b * S_ + 1 + g) * D_ + t]);
        gm[t] = m;
    } else if (t >= 448) {
        int c = t - 448;
        clsf[c] = fmaxf(Wl[cls[b] * 64 + c] + bl[c], 0.f);
    }
    __syncthreads();
    int j = t;
    if (j < 512) {
        float acc = bc1[j];
        for (int c = 0; c < 384; c++) acc += gm[c] * Wc1[(size_t)(384 + c) * 512 + j];
        for (int c = 0; c < 64; c++) acc += clsf[c] * Wc1[(size_t)(768 + c) * 512 + j];
        baseb[b * 512 + j] = acc;
    }
}

// ---------------------------------------------------------------- nearest-center assignment per point
__global__ __launch_bounds__(256) void assign_kernel(const float* __restrict__ xyz, int* __restrict__ assign) {
    int b = blockIdx.x >> 3;
    int n = ((blockIdx.x & 7) << 8) + threadIdx.x;
    __shared__ float cs[G_ * 3];
    const float* xb = xyz + (size_t)b * N_ * 3;
    int t = threadIdx.x;
    if (t < G_) {
        cs[t * 3 + 0] = xb[t * 16 * 3 + 0];
        cs[t * 3 + 1] = xb[t * 16 * 3 + 1];
        cs[t * 3 + 2] = xb[t * 16 * 3 + 2];
    }
    __syncthreads();
    float px = xb[n * 3 + 0], py = xb[n * 3 + 1], pz = xb[n * 3 + 2];
    float bd = 1e38f; int bi = 0;
    for (int g = 0; g < G_; g++) {
        float dx = px - cs[g * 3 + 0], dy = py - cs[g * 3 + 1], dz = pz - cs[g * 3 + 2];
        float dd = dx * dx + dy * dy + dz * dz;
        if (dd < bd) { bd = dd; bi = g; }
    }
    assign[(size_t)b * N_ + n] = bi;
}

// ---------------------------------------------------------------- y1 = relu(bn1(...)), packed (main) or f32 (fallback)
__global__ __launch_bounds__(256) void y1_kernel(const float* __restrict__ xyz, const int* __restrict__ assign,
                                                 const float* __restrict__ pf0, const float* __restrict__ pf1,
                                                 const float* __restrict__ baseb,
                                                 const float* __restrict__ Wc1,
                                                 const float* __restrict__ bn1g, const float* __restrict__ bn1b,
                                                 unsigned short* __restrict__ outP, float* __restrict__ outF) {
    int f4 = blockIdx.x * 256 + threadIdx.x;
    int row = f4 >> 7;
    int j = (f4 & 127) << 2;
    int b = row >> 11;
    int a = assign[row];
    size_t po = ((size_t)b * S_ + 1 + a) * 512 + j;
    float4 pf = *(const float4*)(pf0 + po);
    if (pf1) {
        const float4 p2 = *(const float4*)(pf1 + po);
        pf.x += p2.x; pf.y += p2.y; pf.z += p2.z; pf.w += p2.w;
    }
    const float4 bs = *(const float4*)(baseb + (size_t)b * 512 + j);
    const float* xp = xyz + (size_t)row * 3;
    float x0 = xp[0], x1 = xp[1], x2 = xp[2];
    const float4 w0 = *(const float4*)(Wc1 + (size_t)832 * 512 + j);
    const float4 w1 = *(const float4*)(Wc1 + (size_t)833 * 512 + j);
    const float4 w2 = *(const float4*)(Wc1 + (size_t)834 * 512 + j);
    const float4 g4 = *(const float4*)(bn1g + j);
    const float4 b4 = *(const float4*)(bn1b + j);
    float rs = 1.0f / sqrtf(1.0f + 1e-5f);
    float o0 = fmaxf(g4.x * rs * (pf.x + bs.x + x0 * w0.x + x1 * w1.x + x2 * w2.x) + b4.x, 0.f);
    float o1 = fmaxf(g4.y * rs * (pf.y + bs.y + x0 * w0.y + x1 * w1.y + x2 * w2.y) + b4.y, 0.f);
    float o2 = fmaxf(g4.z * rs * (pf.z + bs.z + x0 * w0.z + x1 * w1.z + x2 * w2.z) + b4.z, 0.f);
    float o3 = fmaxf(g4.w * rs * (pf.w + bs.w + x0 * w0.w + x1 * w1.w + x2 * w2.w) + b4.w, 0.f);
    if (outP) {
        unsigned short h0, h1, h2, h3, l0, l1, l2, l3;
        split1(o0, h0, l0); split1(o1, h1, l1); split1(o2, h2, l2); split1(o3, h3, l3);
        size_t ix = (((size_t)(row >> 4) * 16 + (j >> 5)) * 64 + (row & 15) + ((j >> 3) & 3) * 16) * 8 + (j & 7);
        *(uint2*)(outP + ix) = make_uint2((unsigned)h0 | ((unsigned)h1 << 16), (unsigned)h2 | ((unsigned)h3 << 16));
        *(uint2*)(outP + ix + 16777216) = make_uint2((unsigned)l0 | ((unsigned)l1 << 16), (unsigned)l2 | ((unsigned)l3 << 16));
    } else {
        *(float4*)(outF + (size_t)row * 512 + j) = make_float4(o0, o1, o2, o3);
    }
}

// ---------------------------------------------------------------- legacy fp32 GEMMs (fallback path)
__global__ __launch_bounds__(256) void gemm64_kernel(const float* __restrict__ A, const float* __restrict__ W,
                                                     const float* __restrict__ bias, const float* __restrict__ resid,
                                                     const float* __restrict__ bng, const float* __restrict__ bnb,
                                                     float* __restrict__ C, int M, int N, int K, int act) {
    __shared__ float As[16][68];
    __shared__ float Bs[16][68];
    int t = threadIdx.x;
    int tx = t & 15, ty = t >> 4;
    int m0 = blockIdx.y * 64, n0 = blockIdx.x * 64;
    int am = t >> 2, aseg = t & 3;
    int brow = t >> 4, bc4 = (t & 15) * 4;
    float acc[4][4] = {};
    int arow = m0 + am;
    bool av_ok = arow < M;
    const float* Ap = A + (size_t)arow * K + aseg * 4;
    for (int k0 = 0; k0 < K; k0 += 16) {
        float4 av = make_float4(0.f, 0.f, 0.f, 0.f);
        if (av_ok) av = *(const float4*)(Ap + k0);
        float4 bv;
        int bcol = n0 + bc4;
        const float* Wp = W + (size_t)(k0 + brow) * N + bcol;
        if (((N & 3) == 0) && (bcol + 3 < N)) bv = *(const float4*)Wp;
        else bv = make_float4(bcol + 0 < N ? Wp[0] : 0.f, bcol + 1 < N ? Wp[1] : 0.f,
                              bcol + 2 < N ? Wp[2] : 0.f, bcol + 3 < N ? Wp[3] : 0.f);
        __syncthreads();
        As[aseg * 4 + 0][am] = av.x; As[aseg * 4 + 1][am] = av.y;
        As[aseg * 4 + 2][am] = av.z; As[aseg * 4 + 3][am] = av.w;
        *(float4*)&Bs[brow][bc4] = bv;
        __syncthreads();
#pragma unroll
        for (int kk = 0; kk < 16; kk++) {
            float4 a = *(const float4*)&As[kk][ty * 4];
            float4 bq = *(const float4*)&Bs[kk][tx * 4];
            float ar[4] = {a.x, a.y, a.z, a.w};
            float br[4] = {bq.x, bq.y, bq.z, bq.w};
#pragma unroll
            for (int i = 0; i < 4; i++)
#pragma unroll
                for (int j = 0; j < 4; j++) acc[i][j] += ar[i] * br[j];
        }
    }
    float rs = 1.0f / sqrtf(1.0f + 1e-5f);
#pragma unroll
    for (int i = 0; i < 4; i++) {
        int row = m0 + ty * 4 + i;
        if (row >= M) continue;
#pragma unroll
        for (int j = 0; j < 4; j++) {
            int col = n0 + tx * 4 + j;
            if (col >= N) continue;
            float v = acc[i][j];
            if (bias) v += bias[col];
            if (act == 1) v = fmaxf(v, 0.f);
            else if (act == 2) v = gelu_f(v);
            else if (act == 3) v = fmaxf(bng[col] * v * rs + bnb[col], 0.f);
            if (resid) v += resid[(size_t)row * N + col];
            C[(size_t)row * N + col] = v;
        }
    }
}

__global__ __launch_bounds__(256) void gemm128_kernel(const float* __restrict__ A, const float* __restrict__ W,
                                                      const float* __restrict__ bias,
                                                      const float* __restrict__ bng, const float* __restrict__ bnb,
                                                      float* __restrict__ C, int M, int N, int K, int act) {
    __shared__ float As[16][132];
    __shared__ float Bs[16][132];
    int t = threadIdx.x;
    int tx = t & 15, ty = t >> 4;
    int m0 = blockIdx.y * 128, n0 = blockIdx.x * 128;
    float acc[8][8] = {};
    int am = t >> 1, aseg = (t & 1) * 8;
    int brow = t >> 4, bc4 = (t & 15) * 4;
    int arow = m0 + am;
    bool av_ok = arow < M;
    const float* Ap = A + (size_t)arow * K + aseg;
    for (int k0 = 0; k0 < K; k0 += 16) {
        float4 a0 = make_float4(0.f, 0.f, 0.f, 0.f), a1 = a0;
        if (av_ok) { a0 = *(const float4*)(Ap + k0); a1 = *(const float4*)(Ap + k0 + 4); }
        const float* Wp = W + (size_t)(k0 + brow) * N + n0;
        float4 b0 = *(const float4*)(Wp + bc4);
        float4 b1 = *(const float4*)(Wp + bc4 + 64);
        __syncthreads();
        As[aseg + 0][am] = a0.x; As[aseg + 1][am] = a0.y; As[aseg + 2][am] = a0.z; As[aseg + 3][am] = a0.w;
        As[aseg + 4][am] = a1.x; As[aseg + 5][am] = a1.y; As[aseg + 6][am] = a1.z; As[aseg + 7][am] = a1.w;
        *(float4*)&Bs[brow][bc4] = b0;
        *(float4*)&Bs[brow][bc4 + 64] = b1;
        __syncthreads();
#pragma unroll
        for (int kk = 0; kk < 16; kk++) {
            float4 a0r = *(const float4*)&As[kk][ty * 4];
            float4 a1r = *(const float4*)&As[kk][ty * 4 + 64];
            float4 b0r = *(const float4*)&Bs[kk][tx * 4];
            float4 b1r = *(const float4*)&Bs[kk][tx * 4 + 64];
            float ar[8] = {a0r.x, a0r.y, a0r.z, a0r.w, a1r.x, a1r.y, a1r.z, a1r.w};
            float br[8] = {b0r.x, b0r.y, b0r.z, b0r.w, b1r.x, b1r.y, b1r.z, b1r.w};
#pragma unroll
            for (int i = 0; i < 8; i++)
#pragma unroll
                for (int j = 0; j < 8; j++) acc[i][j] += ar[i] * br[j];
        }
    }
    float rs = 1.0f / sqrtf(1.0f + 1e-5f);
#pragma unroll
    for (int i = 0; i < 8; i++) {
        int row = m0 + ((i < 4) ? (ty * 4 + i) : (ty * 4 + 64 + (i - 4)));
        if (row >= M) continue;
#pragma unroll
        for (int j = 0; j < 8; j++) {
            int col = n0 + ((j < 4) ? (tx * 4 + j) : (tx * 4 + 64 + (j - 4)));
            if (col >= N) continue;
            float v = acc[i][j];
            if (bias) v += bias[col];
            if (act == 3) v = fmaxf(bng[col] * v * rs + bnb[col], 0.f);
            else if (act == 1) v = fmaxf(v, 0.f);
            C[(size_t)row * N + col] = v;
        }
    }
}

// ---------------------------------------------------------------- host
extern "C" void kernel_launch(void* const* d_in, const int* in_sizes, int n_in,
                              void* d_out, int out_size, void* d_ws, size_t ws_size,
                              hipStream_t stream) {
    (void)in_sizes; (void)n_in; (void)out_size;
    const float* xyz    = (const float*)d_in[0];
    const int*   cls    = (const int*)d_in[1];
    const float* We1    = (const float*)d_in[2];
    const float* be1    = (const float*)d_in[3];
    const float* We2    = (const float*)d_in[4];
    const float* be2    = (const float*)d_in[5];
    const float* Wp1    = (const float*)d_in[6];
    const float* bp1    = (const float*)d_in[7];
    const float* Wp2    = (const float*)d_in[8];
    const float* bp2    = (const float*)d_in[9];
    const float* bos    = (const float*)d_in[10];
    const float* eos    = (const float*)d_in[11];
    const float* te     = (const float*)d_in[12];
    const float* ln1_g  = (const float*)d_in[13];
    const float* ln1_b  = (const float*)d_in[14];
    const float* Wqkv   = (const float*)d_in[15];
    const float* bqkv   = (const float*)d_in[16];
    const float* Wo     = (const float*)d_in[17];
    const float* bo     = (const float*)d_in[18];
    const float* ln2_g  = (const float*)d_in[19];
    const float* ln2_b  = (const float*)d_in[20];
    const float* Wf1    = (const float*)d_in[21];
    const float* bf1    = (const float*)d_in[22];
    const float* Wf2    = (const float*)d_in[23];
    const float* bf2    = (const float*)d_in[24];
    const float* lnf_g  = (const float*)d_in[25];
    const float* lnf_b  = (const float*)d_in[26];
    const float* Wl     = (const float*)d_in[27];
    const float* bl     = (const float*)d_in[28];
    const float* Wc1    = (const float*)d_in[29];
    const float* bc1    = (const float*)d_in[30];
    const float* bn1_g  = (const float*)d_in[31];
    const float* bn1_b  = (const float*)d_in[32];
    const float* Wc2    = (const float*)d_in[33];
    const float* bc2    = (const float*)d_in[34];
    const float* bn2_g  = (const float*)d_in[35];
    const float* bn2_b  = (const float*)d_in[36];
    const float* Wc3    = (const float*)d_in[37];
    const float* bc3    = (const float*)d_in[38];
    float* out = (float*)d_out;

    float* ws = (float*)d_ws;
    size_t off = 0;
    auto alloc = [&](size_t nf) { float* p = ws + off; off += nf; return p; };
    float* x      = alloc((size_t)2080 * 384);
    float* hh     = alloc((size_t)2080 * 384);
    float* baseb  = alloc(16 * 512);
    int*   idx    = (int*)alloc((size_t)2048 * 32);
    int*   assign = (int*)alloc(32768);
    unsigned short* hhP = (unsigned short*)alloc(798720);
    float* regionB = alloc(9584640);
    float* y1R    = alloc((size_t)16777216);      // y1 packed planes (or f32 fallback); also tokens pre-phase
    unsigned short* qkvP = (unsigned short*)alloc(5308416);
    unsigned short* woP  = (unsigned short*)alloc(1769472);
    unsigned short* f1P  = (unsigned short*)alloc(7077888);
    unsigned short* f2P  = (unsigned short*)alloc(7077888);
    unsigned short* wc1P = (unsigned short*)alloc(196608);
    unsigned short* wc2P = (unsigned short*)alloc(131072);
    unsigned short* wc3P = (unsigned short*)alloc(16384);
    size_t need_bytes = off * 4;

    float* tokens = y1R;
    unsigned short* y1P = (unsigned short*)y1R;
    const size_t QS = (size_t)2080 * 1152;       // qkv partial stride
    const size_t FS = (size_t)2080 * 384;        // proj/f2 partial stride
    unsigned short* hidP = (unsigned short*)regionB;
    float* f2Pt = regionB + 3194880;             // f2 partials (4 slots)
    unsigned short* y2P = (unsigned short*)regionB;
    const size_t PFS = (size_t)2080 * 512;       // pfp partial stride

    if (ws_size >= need_bytes) {
        packall_kernel<<<dim3(10536), 256, 0, stream>>>(Wqkv, Wo, Wf1, Wf2, Wc1, Wc2, Wc3,
                                                        qkvP, woP, f1P, f2P, wc1P, wc2P, wc3P);
        knn_kernel<<<dim3(2048), dim3(256), 0, stream>>>(xyz, idx);
        tokens_kernel<<<dim3(2048), dim3(128), 0, stream>>>(xyz, idx, We1, be1, We2, be2, tokens);
        buildx_kernel<<<dim3(2080), dim3(128), 0, stream>>>(xyz, tokens, Wp1, bp1, Wp2, bp2, bos, eos, te, x);

        for (int l = 0; l < L_; l++) {
            if (l == 0)
                ln_kernel<<<dim3(520), dim3(256), 0, stream>>>(x, nullptr, nullptr, nullptr, nullptr, nullptr,
                                                               nullptr, ln1_g, ln1_b, hhP, nullptr, 2080);
            else
                ln_kernel<<<dim3(520), dim3(256), 0, stream>>>(x, x, f2Pt, f2Pt + FS, f2Pt + 2 * FS, f2Pt + 3 * FS,
                                                               bf2 + (l - 1) * 384, ln1_g + l * 384, ln1_b + l * 384,
                                                               hhP, nullptr, 2080);
            gemm_pk<2, 4, 2, 0, 0><<<dim3(9, 65, 2), dim3(128), 0, stream>>>(
                hhP, qkvP + (size_t)l * 884736, 130, 72, 12, 6, nullptr, nullptr, nullptr,
                regionB, nullptr, 0, 0, 2080, 1152);
            attn_kernel<<<dim3(768), dim3(256), 0, stream>>>(regionB, regionB + QS, bqkv + l * 1152, hhP, nullptr);
            gemm_pk<2, 2, 2, 0, 0><<<dim3(6, 65, 4), dim3(128), 0, stream>>>(
                hhP, woP + (size_t)l * 294912, 130, 24, 12, 3, nullptr, nullptr, nullptr,
                regionB, nullptr, 0, 0, 2080, 384);
            ln_kernel<<<dim3(520), dim3(256), 0, stream>>>(x, x, regionB, regionB + FS, regionB + 2 * FS, regionB + 3 * FS,
                                                           bo + l * 384, ln2_g + l * 384, ln2_b + l * 384,
                                                           hhP, nullptr, 2080);
            gemm_pk<2, 2, 2, 2, 1><<<dim3(24, 65, 1), dim3(128), 0, stream>>>(
                hhP, f1P + (size_t)l * 1179648, 130, 96, 12, 12, bf1 + l * 1536, nullptr, nullptr,
                nullptr, hidP, 3194880, 48, 2080, 1536);
            gemm_pk<2, 2, 2, 0, 0><<<dim3(6, 65, 4), dim3(128), 0, stream>>>(
                hidP, f2P + (size_t)l * 1179648, 130, 24, 48, 12, nullptr, nullptr, nullptr,
                f2Pt, nullptr, 0, 0, 2080, 384);
        }

        ln_kernel<<<dim3(520), dim3(256), 0, stream>>>(x, nullptr, f2Pt, f2Pt + FS, f2Pt + 2 * FS, f2Pt + 3 * FS,
                                                       bf2 + 11 * 384, lnf_g, lnf_b, hhP, hh, 2080);
        gmaxbase_kernel<<<dim3(16), dim3(512), 0, stream>>>(hh, cls, Wl, bl, Wc1, bc1, baseb);
        gemm_pk<2, 2, 2, 0, 0><<<dim3(8, 65, 2), dim3(128), 0, stream>>>(
            hhP, wc1P, 130, 32, 12, 6, nullptr, nullptr, nullptr, regionB, nullptr, 0, 0, 2080, 512);
        assign_kernel<<<dim3(128), dim3(256), 0, stream>>>(xyz, assign);
        y1_kernel<<<dim3(16384), dim3(256), 0, stream>>>(xyz, assign, regionB, regionB + PFS,
                                                         baseb, Wc1, bn1_g, bn1_b, y1P, nullptr);
        gemm_pk<2, 4, 4, 3, 1><<<dim3(1, 1024, 1), dim3(256), 0, stream>>>(
            y1P, wc2P, 2048, 16, 16, 16, bc2, bn2_g, bn2_b, nullptr, y2P, 8388608, 8, 32768, 256);
        gemm_pk<2, 1, 4, 0, 0><<<dim3(1, 1024, 1), dim3(256), 0, stream>>>(
            y2P, wc3P, 2048, 4, 8, 8, bc3, nullptr, nullptr, out, nullptr, 0, 0, 32768, 50);
    } else {
        // -------- fallback: fp32 path --------
        float* qkvb = regionB;
        float* obuf = regionB + QS;
        float* hid  = regionB;
        float* pfp  = regionB;
        float* y2f  = regionB;
        float* y1f  = y1R;
        knn_kernel<<<dim3(2048), dim3(256), 0, stream>>>(xyz, idx);
        tokens_kernel<<<dim3(2048), dim3(128), 0, stream>>>(xyz, idx, We1, be1, We2, be2, tokens);
        buildx_kernel<<<dim3(2080), dim3(128), 0, stream>>>(xyz, tokens, Wp1, bp1, Wp2, bp2, bos, eos, te, x);
        for (int l = 0; l < L_; l++) {
            ln_kernel<<<dim3(520), dim3(256), 0, stream>>>(x, nullptr, nullptr, nullptr, nullptr, nullptr, nullptr,
                                                           ln1_g + l * 384, ln1_b + l * 384, nullptr, hh, 2080);
            gemm64_kernel<<<dim3(18, 33), dim3(256), 0, stream>>>(hh, Wqkv + (size_t)l * 384 * 1152, bqkv + l * 1152,
                                                                  nullptr, nullptr, nullptr, qkvb, 2080, 1152, 384, 0);
            attn_kernel<<<dim3(768), dim3(256), 0, stream>>>(qkvb, nullptr, nullptr, nullptr, obuf);
            gemm64_kernel<<<dim3(6, 33), dim3(256), 0, stream>>>(obuf, Wo + (size_t)l * 384 * 384, bo + l * 384,
                                                                 x, nullptr, nullptr, x, 2080, 384, 384, 0);
            ln_kernel<<<dim3(520), dim3(256), 0, stream>>>(x, nullptr, nullptr, nullptr, nullptr, nullptr, nullptr,
                                                           ln2_g + l * 384, ln2_b + l * 384, nullptr, hh, 2080);
            gemm64_kernel<<<dim3(24, 33), dim3(256), 0, stream>>>(hh, Wf1 + (size_t)l * 384 * 1536, bf1 + l * 1536,
                                                                  nullptr, nullptr, nullptr, hid, 2080, 1536, 384, 2);
            gemm64_kernel<<<dim3(6, 33), dim3(256), 0, stream>>>(hid, Wf2 + (size_t)l * 1536 * 384, bf2 + l * 384,
                                                                 x, nullptr, nullptr, x, 2080, 384, 1536, 0);
        }
        ln_kernel<<<dim3(520), dim3(256), 0, stream>>>(x, nullptr, nullptr, nullptr, nullptr, nullptr, nullptr,
                                                       lnf_g, lnf_b, nullptr, hh, 2080);
        gmaxbase_kernel<<<dim3(16), dim3(512), 0, stream>>>(hh, cls, Wl, bl, Wc1, bc1, baseb);
        gemm64_kernel<<<dim3(8, 33), dim3(256), 0, stream>>>(hh, Wc1, nullptr, nullptr, nullptr, nullptr,
                                                             pfp, 2080, 512, 384, 0);
        assign_kernel<<<dim3(128), dim3(256), 0, stream>>>(xyz, assign);
        y1_kernel<<<dim3(16384), dim3(256), 0, stream>>>(xyz, assign, pfp, nullptr, baseb, Wc1, bn1_g, bn1_b,
                                                         nullptr, y1f);
        gemm128_kernel<<<dim3(2, 256), dim3(256), 0, stream>>>(y1f, Wc2, bc2, bn2_g, bn2_b, y2f, 32768, 256, 512, 3);
        gemm64_kernel<<<dim3(1, 512), dim3(256), 0, stream>>>(y2f, Wc3, bc3, nullptr, nullptr, nullptr,
                                                              out, 32768, 50, 256, 0);
    }
}

// Round 8
// 2230.727 us; speedup vs baseline: 1.1193x; 1.1193x over previous
//
#include <hip/hip_runtime.h>
#include <math.h>

#define B_   16
#define N_   2048
#define G_   128
#define K_   32
#define D_   384
#define L_   12
#define H_   6
#define DH_  64
#define DFF_ 1536
#define S_   130
#define NP_  50
#define NC_  16
#define LD_  64

typedef __attribute__((ext_vector_type(8))) short bf16x8;
typedef __attribute__((ext_vector_type(4))) float f32x4;

// ---------------------------------------------------------------- utilities
__device__ __forceinline__ float gelu_f(float x) {
    float u = 0.7978845608028654f * (x + 0.044715f * x * x * x);
    float t = 1.f - 2.f / (1.f + __expf(2.f * u));   // tanh(u)
    return 0.5f * x * (1.f + t);
}

__device__ __forceinline__ void split1(float a, unsigned short& hi, unsigned short& lo) {
    unsigned u = __float_as_uint(a);
    unsigned r = (u + 0x7fffu + ((u >> 16) & 1u)) & 0xffff0000u;
    hi = (unsigned short)(r >> 16);
    float al = a - __uint_as_float(r);
    unsigned u2 = __float_as_uint(al);
    lo = (unsigned short)((u2 + 0x7fffu + ((u2 >> 16) & 1u)) >> 16);
}

__device__ __forceinline__ void split8(const float* v, bf16x8& hi, bf16x8& lo) {
#pragma unroll
    for (int e = 0; e < 8; e++) {
        unsigned short h, l;
        split1(v[e], h, l);
        hi[e] = (short)h; lo[e] = (short)l;
    }
}

#define LMIN(da, pa, db, pb) { bool s_ = ((db) < (da)) || ((db) == (da) && (pb) < (pa)); \
                               (da) = s_ ? (db) : (da); (pa) = s_ ? (pb) : (pa); }

// ---------------------------------------------------------------- KNN: 4 waves x 512 pts local top-32, rank-merge
__global__ __launch_bounds__(256) void knn_kernel(const float* __restrict__ xyz, int* __restrict__ idx) {
    int bg = blockIdx.x;
    int b = bg >> 7, g = bg & 127;
    int t = threadIdx.x, w = t >> 6, lane = t & 63;
    const float* xb = xyz + (size_t)b * N_ * 3;
    float cx = xb[(g * 16) * 3 + 0], cy = xb[(g * 16) * 3 + 1], cz = xb[(g * 16) * 3 + 2];
    float d[8];
#pragma unroll
    for (int i = 0; i < 8; i++) {
        int p = w * 512 + i * 64 + lane;
        float dx = xb[p * 3 + 0] - cx, dy = xb[p * 3 + 1] - cy, dz = xb[p * 3 + 2] - cz;
        d[i] = dx * dx + dy * dy + dz * dz;
    }
    __shared__ float cd[128];
    __shared__ int   cpi[128];
    for (int r = 0; r < K_; r++) {
        float td[4]; int tp[4];
#pragma unroll
        for (int i = 0; i < 4; i++) {
            bool s = d[i + 4] < d[i];
            td[i] = s ? d[i + 4] : d[i];
            tp[i] = (s ? (i + 4) : i) * 64 + lane;
        }
        LMIN(td[0], tp[0], td[2], tp[2]);
        LMIN(td[1], tp[1], td[3], tp[3]);
        LMIN(td[0], tp[0], td[1], tp[1]);
        float bd = td[0]; int bp = tp[0];
#pragma unroll
        for (int off = 1; off < 64; off <<= 1) {
            float od = __shfl_xor(bd, off); int oq = __shfl_xor(bp, off);
            LMIN(bd, bp, od, oq);
        }
        if (lane == 0) { cd[w * 32 + r] = bd; cpi[w * 32 + r] = w * 512 + bp; }
        bool mine = ((bp & 63) == lane);
        int ki = bp >> 6;
#pragma unroll
        for (int i = 0; i < 8; i++) d[i] = (mine && ki == i) ? 1e38f : d[i];
    }
    __syncthreads();
    if (w == 0) {
        float a0 = cd[2 * lane], a1 = cd[2 * lane + 1];
        int p0 = cpi[2 * lane], p1 = cpi[2 * lane + 1];
        int r0 = 0, r1 = 0;
        for (int j = 0; j < 128; j++) {
            float dj = cd[j]; int pj = cpi[j];
            r0 += (dj < a0) || (dj == a0 && pj < p0);
            r1 += (dj < a1) || (dj == a1 && pj < p1);
        }
        int* op = idx + (size_t)bg * K_;
        if (r0 < K_) op[r0] = p0;
        if (r1 < K_) op[r1] = p1;
    }
}

// ---------------------------------------------------------------- group PointNet -> tokens (B,G,D)
__global__ __launch_bounds__(128) void tokens_kernel(const float* __restrict__ xyz, const int* __restrict__ idx,
                                                     const float* __restrict__ We1, const float* __restrict__ be1,
                                                     const float* __restrict__ We2, const float* __restrict__ be2,
                                                     float* __restrict__ tokens) {
    int bg = blockIdx.x;
    int b = bg >> 7, g = bg & 127;
    int t = threadIdx.x;
    __shared__ float rel[32][3];
    __shared__ float maxh[128];
    const float* xb = xyz + (size_t)b * N_ * 3;
    if (t < 32) {
        int p = idx[(size_t)bg * K_ + t];
        rel[t][0] = xb[p * 3 + 0] - xb[g * 16 * 3 + 0];
        rel[t][1] = xb[p * 3 + 1] - xb[g * 16 * 3 + 1];
        rel[t][2] = xb[p * 3 + 2] - xb[g * 16 * 3 + 2];
    }
    __syncthreads();
    float w0 = We1[t], w1 = We1[128 + t], w2 = We1[256 + t], bb = be1[t];
    float mx = -1e38f;
#pragma unroll 8
    for (int k = 0; k < 32; k++) {
        float v = rel[k][0] * w0 + rel[k][1] * w1 + rel[k][2] * w2 + bb;
        v = fmaxf(v, 0.f);
        mx = fmaxf(mx, v);
    }
    maxh[t] = mx;
    __syncthreads();
    float* tok = tokens + (size_t)bg * D_;
    for (int jj = t; jj < D_; jj += 128) {
        float acc = be2[jj];
        for (int c = 0; c < 128; c++) acc += maxh[c] * We2[c * D_ + jj];
        tok[jj] = acc;
    }
}

// ---------------------------------------------------------------- x = seq + type_emb + pos  (B,S,D)
__global__ __launch_bounds__(128) void buildx_kernel(const float* __restrict__ xyz, const float* __restrict__ tokens,
                                                     const float* __restrict__ Wp1, const float* __restrict__ bp1,
                                                     const float* __restrict__ Wp2, const float* __restrict__ bp2,
                                                     const float* __restrict__ bos, const float* __restrict__ eos,
                                                     const float* __restrict__ te, float* __restrict__ x) {
    int bs = blockIdx.x;
    int b = bs / S_, s = bs % S_;
    int t = threadIdx.x;
    __shared__ float h1[128];
    float c0 = 0.f, c1 = 0.f, c2 = 0.f;
    if (s >= 1 && s <= G_) {
        const float* xb = xyz + ((size_t)b * N_ + (size_t)(s - 1) * 16) * 3;
        c0 = xb[0]; c1 = xb[1]; c2 = xb[2];
    }
    h1[t] = fmaxf(c0 * Wp1[t] + c1 * Wp1[128 + t] + c2 * Wp1[256 + t] + bp1[t], 0.f);
    __syncthreads();
    int tid = (s == 0) ? 0 : ((s == S_ - 1) ? 2 : 1);
    float* xr = x + (size_t)bs * D_;
    for (int jj = t; jj < D_; jj += 128) {
        float acc = bp2[jj];
        for (int c = 0; c < 128; c++) acc += h1[c] * Wp2[c * D_ + jj];
        float base = (s == 0) ? bos[jj] : (s == S_ - 1 ? eos[jj] : tokens[((size_t)b * G_ + (s - 1)) * D_ + jj]);
        xr[jj] = base + te[tid * D_ + jj] + acc;
    }
}

// ---------------------------------------------------------------- LayerNorm (+ partial-sum reduce + pack)
__global__ __launch_bounds__(256) void ln_kernel(
    const float* __restrict__ xin, float* __restrict__ xout,
    const float* __restrict__ P0, const float* __restrict__ P1,
    const float* __restrict__ P2, const float* __restrict__ P3,
    const float* __restrict__ addb,
    const float* __restrict__ g, const float* __restrict__ b,
    unsigned short* __restrict__ pout, float* __restrict__ fout, int rows) {
    int r = blockIdx.x * 4 + (threadIdx.x >> 6);
    if (r >= rows) return;
    int lane = threadIdx.x & 63;
    const float* xr = xin + (size_t)r * 384;
    float v[6]; float s = 0.f, s2 = 0.f;
#pragma unroll
    for (int i = 0; i < 6; i++) {
        int c = lane + 64 * i;
        float t = xr[c];
        size_t o = (size_t)r * 384 + c;
        if (P0) t += P0[o] + P1[o];
        if (P2) t += P2[o] + P3[o];
        if (addb) t += addb[c];
        if (xout) xout[o] = t;
        v[i] = t; s += t; s2 += t * t;
    }
#pragma unroll
    for (int off = 1; off < 64; off <<= 1) { s += __shfl_xor(s, off); s2 += __shfl_xor(s2, off); }
    float m = s * (1.f / 384.f);
    float var = s2 * (1.f / 384.f) - m * m;
    float rstd = 1.0f / sqrtf(var + 1e-5f);
    int rl = r & 15, mfo = r >> 4;
#pragma unroll
    for (int i = 0; i < 6; i++) {
        int c = lane + 64 * i;
        float y = (v[i] - m) * rstd * g[c] + b[c];
        if (fout) fout[(size_t)r * 384 + c] = y;
        if (pout) {
            unsigned short hi, lo;
            split1(y, hi, lo);
            size_t ix = (((size_t)mfo * 12 + (c >> 5)) * 64 + rl + ((c >> 3) & 3) * 16) * 8 + (c & 7);
            pout[ix] = hi;
            pout[ix + 798720] = lo;
        }
    }
}

// ---------------------------------------------------------------- pack ALL weights in one launch
__global__ __launch_bounds__(256) void packall_kernel(
    const float* __restrict__ Wqkv, const float* __restrict__ Wo, const float* __restrict__ Wf1,
    const float* __restrict__ Wf2, const float* __restrict__ Wc1, const float* __restrict__ Wc2,
    const float* __restrict__ Wc3,
    unsigned short* __restrict__ qkvP, unsigned short* __restrict__ woP, unsigned short* __restrict__ f1P,
    unsigned short* __restrict__ f2P, unsigned short* __restrict__ wc1P, unsigned short* __restrict__ wc2P,
    unsigned short* __restrict__ wc3P) {
    int id = blockIdx.x;
    const float* src; unsigned short* dst; int Ksz, Nsz, nftot, kb, nxb, loc;
    if (id < 2592)       { loc = id;         src = Wqkv; dst = qkvP; Ksz = 384;  Nsz = 1152; nftot = 72; kb = 12; nxb = 18; }
    else if (id < 3456)  { loc = id - 2592;  src = Wo;   dst = woP;  Ksz = 384;  Nsz = 384;  nftot = 24; kb = 12; nxb = 6;  }
    else if (id < 6912)  { loc = id - 3456;  src = Wf1;  dst = f1P;  Ksz = 384;  Nsz = 1536; nftot = 96; kb = 12; nxb = 24; }
    else if (id < 10368) { loc = id - 6912;  src = Wf2;  dst = f2P;  Ksz = 1536; Nsz = 384;  nftot = 24; kb = 48; nxb = 6;  }
    else if (id < 10464) { loc = id - 10368; src = Wc1;  dst = wc1P; Ksz = 384;  Nsz = 512;  nftot = 32; kb = 12; nxb = 8;  }
    else if (id < 10528) { loc = id - 10464; src = Wc2;  dst = wc2P; Ksz = 512;  Nsz = 256;  nftot = 16; kb = 16; nxb = 4;  }
    else                 { loc = id - 10528; src = Wc3;  dst = wc3P; Ksz = 256;  Nsz = 50;   nftot = 4;  kb = 8;  nxb = 1;  }
    int xb = loc % nxb; int rest = loc / nxb; int kblk = rest % kb; int l = rest / kb;
    src += (size_t)l * Ksz * Nsz;
    dst += (size_t)l * 2 * nftot * kb * 512;
    int nf = xb * 4 + (threadIdx.x >> 6);
    if (nf >= nftot) return;
    int lane = threadIdx.x & 63;
    int n = nf * 16 + (lane & 15);
    int k0 = kblk * 32 + (lane >> 4) * 8;
    float av[8];
#pragma unroll
    for (int j = 0; j < 8; j++)
        av[j] = (n < Nsz) ? src[(size_t)(k0 + j) * Nsz + n] : 0.f;
    bf16x8 hi, lo;
    split8(av, hi, lo);
    size_t slot = ((size_t)nf * kb + kblk) * 512 + lane * 8;
    *(bf16x8*)(dst + slot) = hi;
    *(bf16x8*)(dst + slot + (size_t)nftot * kb * 512) = lo;
}

// ---------------------------------------------------------------- packed-A × packed-B MFMA GEMM
template<int MF, int NF, int WNS, int ACT, int FRAGOUT>
__global__ __launch_bounds__(WNS * 64) void gemm_pk(
    const unsigned short* __restrict__ Ap, const unsigned short* __restrict__ Bp,
    int mftot, int nftot, int kbt, int kbc,
    const float* __restrict__ bias, const float* __restrict__ bng, const float* __restrict__ bnb,
    float* __restrict__ C, unsigned short* __restrict__ Cp, size_t CploS, int ckbt,
    int M, int N) {
    int w = threadIdx.x >> 6, lane = threadIdx.x & 63;
    int mf0 = blockIdx.y * MF;
    int nf0 = (blockIdx.x * WNS + w) * NF;
    int k0 = blockIdx.z * kbc;
    f32x4 acc[MF][NF];
#pragma unroll
    for (int i = 0; i < MF; i++)
#pragma unroll
        for (int j = 0; j < NF; j++) acc[i][j] = (f32x4){0.f, 0.f, 0.f, 0.f};
    const size_t AloS = (size_t)mftot * kbt * 512, BloS = (size_t)nftot * kbt * 512;
    const unsigned short* Ab = Ap + ((size_t)mf0 * kbt + k0) * 512 + lane * 8;
    const unsigned short* Bb = Bp + ((size_t)nf0 * kbt + k0) * 512 + lane * 8;
#pragma unroll 2
    for (int kk = 0; kk < kbc; kk++) {
        bf16x8 ah[MF], al[MF], bh[NF], bl[NF];
#pragma unroll
        for (int i = 0; i < MF; i++) {
            const unsigned short* p = Ab + ((size_t)i * kbt + kk) * 512;
            ah[i] = *(const bf16x8*)p;
            al[i] = *(const bf16x8*)(p + AloS);
        }
#pragma unroll
        for (int j = 0; j < NF; j++) {
            const unsigned short* p = Bb + ((size_t)j * kbt + kk) * 512;
            bh[j] = *(const bf16x8*)p;
            bl[j] = *(const bf16x8*)(p + BloS);
        }
#pragma unroll
        for (int j = 0; j < NF; j++)
#pragma unroll
            for (int i = 0; i < MF; i++) {
                acc[i][j] = __builtin_amdgcn_mfma_f32_16x16x32_bf16(ah[i], bh[j], acc[i][j], 0, 0, 0);
                acc[i][j] = __builtin_amdgcn_mfma_f32_16x16x32_bf16(al[i], bh[j], acc[i][j], 0, 0, 0);
                acc[i][j] = __builtin_amdgcn_mfma_f32_16x16x32_bf16(ah[i], bl[j], acc[i][j], 0, 0, 0);
            }
    }
    int lm = lane & 15, lg = lane >> 4;
    const float rsq = 1.0f / sqrtf(1.0f + 1e-5f);
    float* Cz = C ? (C + (size_t)blockIdx.z * ((size_t)M * N)) : nullptr;
#pragma unroll
    for (int i = 0; i < MF; i++) {
#pragma unroll
        for (int r = 0; r < 4; r++) {
            int row = (mf0 + i) * 16 + lg * 4 + r;
#pragma unroll
            for (int j = 0; j < NF; j++) {
                int col = (nf0 + j) * 16 + lm;
                float v = acc[i][j][r];
                if (bias) v += bias[col];
                if (ACT == 2) v = gelu_f(v);
                else if (ACT == 3) v = fmaxf(bng[col] * v * rsq + bnb[col], 0.f);
                if (FRAGOUT) {
                    unsigned short hi, lo;
                    split1(v, hi, lo);
                    size_t ix = (((size_t)(mf0 + i) * ckbt + (col >> 5)) * 64 + (row & 15) + ((col >> 3) & 3) * 16) * 8 + (col & 7);
                    Cp[ix] = hi;
                    Cp[ix + CploS] = lo;
                } else if (col < N) {
                    Cz[(size_t)row * N + col] = v;
                }
            }
        }
    }
}

// ---------------------------------------------------------------- fused attention: K+V in LDS, 512 thr, 3 q-chunks
// qkv has bias already fused (z=1 GEMM). grid = (B*H*3).
__global__ __launch_bounds__(512) void attn_kernel(const float* __restrict__ Q0,
                                                   unsigned short* __restrict__ outP, float* __restrict__ outF) {
    __shared__ float Ksh[S_ * 65];
    __shared__ float Vsh[S_ * 65];
    __shared__ float att[8][132];
    int blk = blockIdx.x;
    int bh = blk / 3, qc = blk % 3;
    int b = bh / H_, h = bh % H_;
    int t = threadIdx.x, w = t >> 6, lane = t & 63;
    const size_t base = (size_t)b * S_ * 1152;
    for (int e = t; e < S_ * 64; e += 512) {
        int k = e >> 6, d = e & 63;
        Ksh[k * 65 + d] = Q0[base + (size_t)k * 1152 + 384 + h * 64 + d];
        Vsh[k * 65 + d] = Q0[base + (size_t)k * 1152 + 768 + h * 64 + d];
    }
    __syncthreads();
    int q0 = qc * 44;
    int qend = q0 + 44; if (qend > S_) qend = S_;
    int r2 = (lane < 2) ? (128 + lane) : 0;
    for (int q = q0 + w; q < qend; q += 8) {
        float qv = Q0[base + (size_t)q * 1152 + h * 64 + lane];
        float s0 = 0.f, s1 = 0.f, s2 = 0.f;
#pragma unroll 16
        for (int d = 0; d < 64; d++) {
            float qd = __shfl(qv, d);
            s0 += qd * Ksh[lane * 65 + d];
            s1 += qd * Ksh[(lane + 64) * 65 + d];
            s2 += qd * Ksh[r2 * 65 + d];
        }
        s0 *= 0.125f; s1 *= 0.125f; s2 *= 0.125f;
        float m = fmaxf(s0, s1);
        if (lane < 2) m = fmaxf(m, s2);
        for (int off = 1; off < 64; off <<= 1) m = fmaxf(m, __shfl_xor(m, off));
        float e0 = __expf(s0 - m), e1 = __expf(s1 - m);
        float e2 = (lane < 2) ? __expf(s2 - m) : 0.f;
        float l = e0 + e1 + e2;
        for (int off = 1; off < 64; off <<= 1) l += __shfl_xor(l, off);
        float inv = 1.f / l;
        att[w][lane] = e0 * inv;
        att[w][lane + 64] = e1 * inv;
        if (lane < 2) att[w][lane + 128] = e2 * inv;
        float acc = 0.f;
#pragma unroll 10
        for (int k = 0; k < S_; k++) acc += att[w][k] * Vsh[k * 65 + lane];
        int row = b * S_ + q;
        if (outP) {
            unsigned short hi, lo;
            split1(acc, hi, lo);
            size_t ix = (((size_t)(row >> 4) * 12 + (h * 2 + (lane >> 5))) * 64 + (row & 15) + ((lane >> 3) & 3) * 16) * 8 + (lane & 7);
            outP[ix] = hi;
            outP[ix + 798720] = lo;
        } else {
            outF[(size_t)row * D_ + h * 64 + lane] = acc;
        }
    }
}

// ---------------------------------------------------------------- fused: global max over patches -> head base vector
__global__ __launch_bounds__(512) void gmaxbase_kernel(const float* __restrict__ hh, const int* __restrict__ cls,
                                                       const float* __restrict__ Wl, const float* __restrict__ bl,
                                                       const float* __restrict__ Wc1, const float* __restrict__ bc1,
                                                       float* __restrict__ baseb) {
    int b = blockIdx.x;
    int t = threadIdx.x;
    __shared__ float gm[384];
    __shared__ float clsf[64];
    if (t < 384) {
        float m = -1e38f;
        for (int g = 0; g < G_; g++) m = fmaxf(m, hh[((size_t)b * S_ + 1 + g) * D_ + t]);
        gm[t] = m;
    } else if (t >= 448) {
        int c = t - 448;
        clsf[c] = fmaxf(Wl[cls[b] * 64 + c] + bl[c], 0.f);
    }
    __syncthreads();
    int j = t;
    if (j < 512) {
        float acc = bc1[j];
        for (int c = 0; c < 384; c++) acc += gm[c] * Wc1[(size_t)(384 + c) * 512 + j];
        for (int c = 0; c < 64; c++) acc += clsf[c] * Wc1[(size_t)(768 + c) * 512 + j];
        baseb[b * 512 + j] = acc;
    }
}

// ---------------------------------------------------------------- nearest-center assignment per point
__global__ __launch_bounds__(256) void assign_kernel(const float* __restrict__ xyz, int* __restrict__ assign) {
    int b = blockIdx.x >> 3;
    int n = ((blockIdx.x & 7) << 8) + threadIdx.x;
    __shared__ float cs[G_ * 3];
    const float* xb = xyz + (size_t)b * N_ * 3;
    int t = threadIdx.x;
    if (t < G_) {
        cs[t * 3 + 0] = xb[t * 16 * 3 + 0];
        cs[t * 3 + 1] = xb[t * 16 * 3 + 1];
        cs[t * 3 + 2] = xb[t * 16 * 3 + 2];
    }
    __syncthreads();
    float px = xb[n * 3 + 0], py = xb[n * 3 + 1], pz = xb[n * 3 + 2];
    float bd = 1e38f; int bi = 0;
    for (int g = 0; g < G_; g++) {
        float dx = px - cs[g * 3 + 0], dy = py - cs[g * 3 + 1], dz = pz - cs[g * 3 + 2];
        float dd = dx * dx + dy * dy + dz * dz;
        if (dd < bd) { bd = dd; bi = g; }
    }
    assign[(size_t)b * N_ + n] = bi;
}

// ---------------------------------------------------------------- y1 = relu(bn1(...)), packed (main) or f32 (fallback)
__global__ __launch_bounds__(256) void y1_kernel(const float* __restrict__ xyz, const int* __restrict__ assign,
                                                 const float* __restrict__ pf0, const float* __restrict__ pf1,
                                                 const float* __restrict__ baseb,
                                                 const float* __restrict__ Wc1,
                                                 const float* __restrict__ bn1g, const float* __restrict__ bn1b,
                                                 unsigned short* __restrict__ outP, float* __restrict__ outF) {
    int f4 = blockIdx.x * 256 + threadIdx.x;
    int row = f4 >> 7;
    int j = (f4 & 127) << 2;
    int b = row >> 11;
    int a = assign[row];
    size_t po = ((size_t)b * S_ + 1 + a) * 512 + j;
    float4 pf = *(const float4*)(pf0 + po);
    if (pf1) {
        const float4 p2 = *(const float4*)(pf1 + po);
        pf.x += p2.x; pf.y += p2.y; pf.z += p2.z; pf.w += p2.w;
    }
    const float4 bs = *(const float4*)(baseb + (size_t)b * 512 + j);
    const float* xp = xyz + (size_t)row * 3;
    float x0 = xp[0], x1 = xp[1], x2 = xp[2];
    const float4 w0 = *(const float4*)(Wc1 + (size_t)832 * 512 + j);
    const float4 w1 = *(const float4*)(Wc1 + (size_t)833 * 512 + j);
    const float4 w2 = *(const float4*)(Wc1 + (size_t)834 * 512 + j);
    const float4 g4 = *(const float4*)(bn1g + j);
    const float4 b4 = *(const float4*)(bn1b + j);
    float rs = 1.0f / sqrtf(1.0f + 1e-5f);
    float o0 = fmaxf(g4.x * rs * (pf.x + bs.x + x0 * w0.x + x1 * w1.x + x2 * w2.x) + b4.x, 0.f);
    float o1 = fmaxf(g4.y * rs * (pf.y + bs.y + x0 * w0.y + x1 * w1.y + x2 * w2.y) + b4.y, 0.f);
    float o2 = fmaxf(g4.z * rs * (pf.z + bs.z + x0 * w0.z + x1 * w1.z + x2 * w2.z) + b4.z, 0.f);
    float o3 = fmaxf(g4.w * rs * (pf.w + bs.w + x0 * w0.w + x1 * w1.w + x2 * w2.w) + b4.w, 0.f);
    if (outP) {
        unsigned short h0, h1, h2, h3, l0, l1, l2, l3;
        split1(o0, h0, l0); split1(o1, h1, l1); split1(o2, h2, l2); split1(o3, h3, l3);
        size_t ix = (((size_t)(row >> 4) * 16 + (j >> 5)) * 64 + (row & 15) + ((j >> 3) & 3) * 16) * 8 + (j & 7);
        *(uint2*)(outP + ix) = make_uint2((unsigned)h0 | ((unsigned)h1 << 16), (unsigned)h2 | ((unsigned)h3 << 16));
        *(uint2*)(outP + ix + 16777216) = make_uint2((unsigned)l0 | ((unsigned)l1 << 16), (unsigned)l2 | ((unsigned)l3 << 16));
    } else {
        *(float4*)(outF + (size_t)row * 512 + j) = make_float4(o0, o1, o2, o3);
    }
}

// ---------------------------------------------------------------- legacy fp32 GEMMs (fallback path)
__global__ __launch_bounds__(256) void gemm64_kernel(const float* __restrict__ A, const float* __restrict__ W,
                                                     const float* __restrict__ bias, const float* __restrict__ resid,
                                                     const float* __restrict__ bng, const float* __restrict__ bnb,
                                                     float* __restrict__ C, int M, int N, int K, int act) {
    __shared__ float As[16][68];
    __shared__ float Bs[16][68];
    int t = threadIdx.x;
    int tx = t & 15, ty = t >> 4;
    int m0 = blockIdx.y * 64, n0 = blockIdx.x * 64;
    int am = t >> 2, aseg = t & 3;
    int brow = t >> 4, bc4 = (t & 15) * 4;
    float acc[4][4] = {};
    int arow = m0 + am;
    bool av_ok = arow < M;
    const float* Ap = A + (size_t)arow * K + aseg * 4;
    for (int k0 = 0; k0 < K; k0 += 16) {
        float4 av = make_float4(0.f, 0.f, 0.f, 0.f);
        if (av_ok) av = *(const float4*)(Ap + k0);
        float4 bv;
        int bcol = n0 + bc4;
        const float* Wp = W + (size_t)(k0 + brow) * N + bcol;
        if (((N & 3) == 0) && (bcol + 3 < N)) bv = *(const float4*)Wp;
        else bv = make_float4(bcol + 0 < N ? Wp[0] : 0.f, bcol + 1 < N ? Wp[1] : 0.f,
                              bcol + 2 < N ? Wp[2] : 0.f, bcol + 3 < N ? Wp[3] : 0.f);
        __syncthreads();
        As[aseg * 4 + 0][am] = av.x; As[aseg * 4 + 1][am] = av.y;
        As[aseg * 4 + 2][am] = av.z; As[aseg * 4 + 3][am] = av.w;
        *(float4*)&Bs[brow][bc4] = bv;
        __syncthreads();
#pragma unroll
        for (int kk = 0; kk < 16; kk++) {
            float4 a = *(const float4*)&As[kk][ty * 4];
            float4 bq = *(const float4*)&Bs[kk][tx * 4];
            float ar[4] = {a.x, a.y, a.z, a.w};
            float br[4] = {bq.x, bq.y, bq.z, bq.w};
#pragma unroll
            for (int i = 0; i < 4; i++)
#pragma unroll
                for (int j = 0; j < 4; j++) acc[i][j] += ar[i] * br[j];
        }
    }
    float rs = 1.0f / sqrtf(1.0f + 1e-5f);
#pragma unroll
    for (int i = 0; i < 4; i++) {
        int row = m0 + ty * 4 + i;
        if (row >= M) continue;
#pragma unroll
        for (int j = 0; j < 4; j++) {
            int col = n0 + tx * 4 + j;
            if (col >= N) continue;
            float v = acc[i][j];
            if (bias) v += bias[col];
            if (act == 1) v = fmaxf(v, 0.f);
            else if (act == 2) v = gelu_f(v);
            else if (act == 3) v = fmaxf(bng[col] * v * rs + bnb[col], 0.f);
            if (resid) v += resid[(size_t)row * N + col];
            C[(size_t)row * N + col] = v;
        }
    }
}

__global__ __launch_bounds__(256) void gemm128_kernel(const float* __restrict__ A, const float* __restrict__ W,
                                                      const float* __restrict__ bias,
                                                      const float* __restrict__ bng, const float* __restrict__ bnb,
                                                      float* __restrict__ C, int M, int N, int K, int act) {
    __shared__ float As[16][132];
    __shared__ float Bs[16][132];
    int t = threadIdx.x;
    int tx = t & 15, ty = t >> 4;
    int m0 = blockIdx.y * 128, n0 = blockIdx.x * 128;
    float acc[8][8] = {};
    int am = t >> 1, aseg = (t & 1) * 8;
    int brow = t >> 4, bc4 = (t & 15) * 4;
    int arow = m0 + am;
    bool av_ok = arow < M;
    const float* Ap = A + (size_t)arow * K + aseg;
    for (int k0 = 0; k0 < K; k0 += 16) {
        float4 a0 = make_float4(0.f, 0.f, 0.f, 0.f), a1 = a0;
        if (av_ok) { a0 = *(const float4*)(Ap + k0); a1 = *(const float4*)(Ap + k0 + 4); }
        const float* Wp = W + (size_t)(k0 + brow) * N + n0;
        float4 b0 = *(const float4*)(Wp + bc4);
        float4 b1 = *(const float4*)(Wp + bc4 + 64);
        __syncthreads();
        As[aseg + 0][am] = a0.x; As[aseg + 1][am] = a0.y; As[aseg + 2][am] = a0.z; As[aseg + 3][am] = a0.w;
        As[aseg + 4][am] = a1.x; As[aseg + 5][am] = a1.y; As[aseg + 6][am] = a1.z; As[aseg + 7][am] = a1.w;
        *(float4*)&Bs[brow][bc4] = b0;
        *(float4*)&Bs[brow][bc4 + 64] = b1;
        __syncthreads();
#pragma unroll
        for (int kk = 0; kk < 16; kk++) {
            float4 a0r = *(const float4*)&As[kk][ty * 4];
            float4 a1r = *(const float4*)&As[kk][ty * 4 + 64];
            float4 b0r = *(const float4*)&Bs[kk][tx * 4];
            float4 b1r = *(const float4*)&Bs[kk][tx * 4 + 64];
            float ar[8] = {a0r.x, a0r.y, a0r.z, a0r.w, a1r.x, a1r.y, a1r.z, a1r.w};
            float br[8] = {b0r.x, b0r.y, b0r.z, b0r.w, b1r.x, b1r.y, b1r.z, b1r.w};
#pragma unroll
            for (int i = 0; i < 8; i++)
#pragma unroll
                for (int j = 0; j < 8; j++) acc[i][j] += ar[i] * br[j];
        }
    }
    float rs = 1.0f / sqrtf(1.0f + 1e-5f);
#pragma unroll
    for (int i = 0; i < 8; i++) {
        int row = m0 + ((i < 4) ? (ty * 4 + i) : (ty * 4 + 64 + (i - 4)));
        if (row >= M) continue;
#pragma unroll
        for (int j = 0; j < 8; j++) {
            int col = n0 + ((j < 4) ? (tx * 4 + j) : (tx * 4 + 64 + (j - 4)));
            if (col >= N) continue;
            float v = acc[i][j];
            if (bias) v += bias[col];
            if (act == 3) v = fmaxf(bng[col] * v * rs + bnb[col], 0.f);
            else if (act == 1) v = fmaxf(v, 0.f);
            C[(size_t)row * N + col] = v;
        }
    }
}

// ---------------------------------------------------------------- host
extern "C" void kernel_launch(void* const* d_in, const int* in_sizes, int n_in,
                              void* d_out, int out_size, void* d_ws, size_t ws_size,
                              hipStream_t stream) {
    (void)in_sizes; (void)n_in; (void)out_size;
    const float* xyz    = (const float*)d_in[0];
    const int*   cls    = (const int*)d_in[1];
    const float* We1    = (const float*)d_in[2];
    const float* be1    = (const float*)d_in[3];
    const float* We2    = (const float*)d_in[4];
    const float* be2    = (const float*)d_in[5];
    const float* Wp1    = (const float*)d_in[6];
    const float* bp1    = (const float*)d_in[7];
    const float* Wp2    = (const float*)d_in[8];
    const float* bp2    = (const float*)d_in[9];
    const float* bos    = (const float*)d_in[10];
    const float* eos    = (const float*)d_in[11];
    const float* te     = (const float*)d_in[12];
    const float* ln1_g  = (const float*)d_in[13];
    const float* ln1_b  = (const float*)d_in[14];
    const float* Wqkv   = (const float*)d_in[15];
    const float* bqkv   = (const float*)d_in[16];
    const float* Wo     = (const float*)d_in[17];
    const float* bo     = (const float*)d_in[18];
    const float* ln2_g  = (const float*)d_in[19];
    const float* ln2_b  = (const float*)d_in[20];
    const float* Wf1    = (const float*)d_in[21];
    const float* bf1    = (const float*)d_in[22];
    const float* Wf2    = (const float*)d_in[23];
    const float* bf2    = (const float*)d_in[24];
    const float* lnf_g  = (const float*)d_in[25];
    const float* lnf_b  = (const float*)d_in[26];
    const float* Wl     = (const float*)d_in[27];
    const float* bl     = (const float*)d_in[28];
    const float* Wc1    = (const float*)d_in[29];
    const float* bc1    = (const float*)d_in[30];
    const float* bn1_g  = (const float*)d_in[31];
    const float* bn1_b  = (const float*)d_in[32];
    const float* Wc2    = (const float*)d_in[33];
    const float* bc2    = (const float*)d_in[34];
    const float* bn2_g  = (const float*)d_in[35];
    const float* bn2_b  = (const float*)d_in[36];
    const float* Wc3    = (const float*)d_in[37];
    const float* bc3    = (const float*)d_in[38];
    float* out = (float*)d_out;

    float* ws = (float*)d_ws;
    size_t off = 0;
    auto alloc = [&](size_t nf) { float* p = ws + off; off += nf; return p; };
    float* x      = alloc((size_t)2080 * 384);
    float* hh     = alloc((size_t)2080 * 384);
    float* baseb  = alloc(16 * 512);
    int*   idx    = (int*)alloc((size_t)2048 * 32);
    int*   assign = (int*)alloc(32768);
    unsigned short* hhP = (unsigned short*)alloc(798720);
    float* regionB = alloc(9584640);
    float* y1R    = alloc((size_t)16777216);      // y1 packed planes (or f32 fallback); also tokens pre-phase
    unsigned short* qkvP = (unsigned short*)alloc(5308416);
    unsigned short* woP  = (unsigned short*)alloc(1769472);
    unsigned short* f1P  = (unsigned short*)alloc(7077888);
    unsigned short* f2P  = (unsigned short*)alloc(7077888);
    unsigned short* wc1P = (unsigned short*)alloc(196608);
    unsigned short* wc2P = (unsigned short*)alloc(131072);
    unsigned short* wc3P = (unsigned short*)alloc(16384);
    size_t need_bytes = off * 4;

    float* tokens = y1R;
    unsigned short* y1P = (unsigned short*)y1R;
    const size_t FS = (size_t)2080 * 384;        // proj/f2 partial stride
    unsigned short* hidP = (unsigned short*)regionB;
    float* f2Pt = regionB + 3194880;             // f2 partials (4 slots)
    unsigned short* y2P = (unsigned short*)regionB;
    const size_t PFS = (size_t)2080 * 512;       // pfp partial stride

    if (ws_size >= need_bytes) {
        packall_kernel<<<dim3(10536), 256, 0, stream>>>(Wqkv, Wo, Wf1, Wf2, Wc1, Wc2, Wc3,
                                                        qkvP, woP, f1P, f2P, wc1P, wc2P, wc3P);
        knn_kernel<<<dim3(2048), dim3(256), 0, stream>>>(xyz, idx);
        tokens_kernel<<<dim3(2048), dim3(128), 0, stream>>>(xyz, idx, We1, be1, We2, be2, tokens);
        buildx_kernel<<<dim3(2080), dim3(128), 0, stream>>>(xyz, tokens, Wp1, bp1, Wp2, bp2, bos, eos, te, x);

        for (int l = 0; l < L_; l++) {
            if (l == 0)
                ln_kernel<<<dim3(520), dim3(256), 0, stream>>>(x, nullptr, nullptr, nullptr, nullptr, nullptr,
                                                               nullptr, ln1_g, ln1_b, hhP, nullptr, 2080);
            else
                ln_kernel<<<dim3(520), dim3(256), 0, stream>>>(x, x, f2Pt, f2Pt + FS, f2Pt + 2 * FS, f2Pt + 3 * FS,
                                                               bf2 + (l - 1) * 384, ln1_g + l * 384, ln1_b + l * 384,
                                                               hhP, nullptr, 2080);
            gemm_pk<2, 2, 2, 0, 0><<<dim3(18, 65, 1), dim3(128), 0, stream>>>(
                hhP, qkvP + (size_t)l * 884736, 130, 72, 12, 12, bqkv + l * 1152, nullptr, nullptr,
                regionB, nullptr, 0, 0, 2080, 1152);
            attn_kernel<<<dim3(288), dim3(512), 0, stream>>>(regionB, hhP, nullptr);
            gemm_pk<2, 2, 2, 0, 0><<<dim3(6, 65, 4), dim3(128), 0, stream>>>(
                hhP, woP + (size_t)l * 294912, 130, 24, 12, 3, nullptr, nullptr, nullptr,
                regionB, nullptr, 0, 0, 2080, 384);
            ln_kernel<<<dim3(520), dim3(256), 0, stream>>>(x, x, regionB, regionB + FS, regionB + 2 * FS, regionB + 3 * FS,
                                                           bo + l * 384, ln2_g + l * 384, ln2_b + l * 384,
                                                           hhP, nullptr, 2080);
            gemm_pk<2, 2, 2, 2, 1><<<dim3(24, 65, 1), dim3(128), 0, stream>>>(
                hhP, f1P + (size_t)l * 1179648, 130, 96, 12, 12, bf1 + l * 1536, nullptr, nullptr,
                nullptr, hidP, 3194880, 48, 2080, 1536);
            gemm_pk<2, 2, 2, 0, 0><<<dim3(6, 65, 4), dim3(128), 0, stream>>>(
                hidP, f2P + (size_t)l * 1179648, 130, 24, 48, 12, nullptr, nullptr, nullptr,
                f2Pt, nullptr, 0, 0, 2080, 384);
        }

        ln_kernel<<<dim3(520), dim3(256), 0, stream>>>(x, nullptr, f2Pt, f2Pt + FS, f2Pt + 2 * FS, f2Pt + 3 * FS,
                                                       bf2 + 11 * 384, lnf_g, lnf_b, hhP, hh, 2080);
        gmaxbase_kernel<<<dim3(16), dim3(512), 0, stream>>>(hh, cls, Wl, bl, Wc1, bc1, baseb);
        gemm_pk<2, 2, 2, 0, 0><<<dim3(8, 65, 2), dim3(128), 0, stream>>>(
            hhP, wc1P, 130, 32, 12, 6, nullptr, nullptr, nullptr, regionB, nullptr, 0, 0, 2080, 512);
        assign_kernel<<<dim3(128), dim3(256), 0, stream>>>(xyz, assign);
        y1_kernel<<<dim3(16384), dim3(256), 0, stream>>>(xyz, assign, regionB, regionB + PFS,
                                                         baseb, Wc1, bn1_g, bn1_b, y1P, nullptr);
        gemm_pk<2, 4, 4, 3, 1><<<dim3(1, 1024, 1), dim3(256), 0, stream>>>(
            y1P, wc2P, 2048, 16, 16, 16, bc2, bn2_g, bn2_b, nullptr, y2P, 8388608, 8, 32768, 256);
        gemm_pk<2, 1, 4, 0, 0><<<dim3(1, 1024, 1), dim3(256), 0, stream>>>(
            y2P, wc3P, 2048, 4, 8, 8, bc3, nullptr, nullptr, out, nullptr, 0, 0, 32768, 50);
    } else {
        // -------- fallback: fp32 path --------
        float* qkvb = regionB;
        float* obuf = regionB + (size_t)2080 * 1152;
        float* hid  = regionB;
        float* pfp  = regionB;
        float* y2f  = regionB;
        float* y1f  = y1R;
        knn_kernel<<<dim3(2048), dim3(256), 0, stream>>>(xyz, idx);
        tokens_kernel<<<dim3(2048), dim3(128), 0, stream>>>(xyz, idx, We1, be1, We2, be2, tokens);
        buildx_kernel<<<dim3(2080), dim3(128), 0, stream>>>(xyz, tokens, Wp1, bp1, Wp2, bp2, bos, eos, te, x);
        for (int l = 0; l < L_; l++) {
            ln_kernel<<<dim3(520), dim3(256), 0, stream>>>(x, nullptr, nullptr, nullptr, nullptr, nullptr, nullptr,
                                                           ln1_g + l * 384, ln1_b + l * 384, nullptr, hh, 2080);
            gemm64_kernel<<<dim3(18, 33), dim3(256), 0, stream>>>(hh, Wqkv + (size_t)l * 384 * 1152, bqkv + l * 1152,
                                                                  nullptr, nullptr, nullptr, qkvb, 2080, 1152, 384, 0);
            attn_kernel<<<dim3(288), dim3(512), 0, stream>>>(qkvb, nullptr, obuf);
            gemm64_kernel<<<dim3(6, 33), dim3(256), 0, stream>>>(obuf, Wo + (size_t)l * 384 * 384, bo + l * 384,
                                                                 x, nullptr, nullptr, x, 2080, 384, 384, 0);
            ln_kernel<<<dim3(520), dim3(256), 0, stream>>>(x, nullptr, nullptr, nullptr, nullptr, nullptr, nullptr,
                                                           ln2_g + l * 384, ln2_b + l * 384, nullptr, hh, 2080);
            gemm64_kernel<<<dim3(24, 33), dim3(256), 0, stream>>>(hh, Wf1 + (size_t)l * 384 * 1536, bf1 + l * 1536,
                                                                  nullptr, nullptr, nullptr, hid, 2080, 1536, 384, 2);
            gemm64_kernel<<<dim3(6, 33), dim3(256), 0, stream>>>(hid, Wf2 + (size_t)l * 1536 * 384, bf2 + l * 384,
                                                                 x, nullptr, nullptr, x, 2080, 384, 1536, 0);
        }
        ln_kernel<<<dim3(520), dim3(256), 0, stream>>>(x, nullptr, nullptr, nullptr, nullptr, nullptr, nullptr,
                                                       lnf_g, lnf_b, nullptr, hh, 2080);
        gmaxbase_kernel<<<dim3(16), dim3(512), 0, stream>>>(hh, cls, Wl, bl, Wc1, bc1, baseb);
        gemm64_kernel<<<dim3(8, 33), dim3(256), 0, stream>>>(hh, Wc1, nullptr, nullptr, nullptr, nullptr,
                                                             pfp, 2080, 512, 384, 0);
        assign_kernel<<<dim3(128), dim3(256), 0, stream>>>(xyz, assign);
        y1_kernel<<<dim3(16384), dim3(256), 0, stream>>>(xyz, assign, pfp, nullptr, baseb, Wc1, bn1_g, bn1_b,
                                                         nullptr, y1f);
        gemm128_kernel<<<dim3(2, 256), dim3(256), 0, stream>>>(y1f, Wc2, bc2, bn2_g, bn2_b, y2f, 32768, 256, 512, 3);
        gemm64_kernel<<<dim3(1, 512), dim3(256), 0, stream>>>(y2f, Wc3, bc3, nullptr, nullptr, nullptr,
                                                              out, 32768, 50, 256, 0);
    }
}

// Round 9
// 1709.581 us; speedup vs baseline: 1.4605x; 1.3048x over previous
//
#include <hip/hip_runtime.h>
#include <math.h>

#define B_   16
#define N_   2048
#define G_   128
#define K_   32
#define D_   384
#define L_   12
#define H_   6
#define DH_  64
#define DFF_ 1536
#define S_   130
#define NP_  50
#define NC_  16
#define LD_  64

typedef __attribute__((ext_vector_type(8))) short bf16x8;
typedef __attribute__((ext_vector_type(4))) float f32x4;

// ---------------------------------------------------------------- utilities
__device__ __forceinline__ float gelu_f(float x) {
    float u = 0.7978845608028654f * (x + 0.044715f * x * x * x);
    float t = 1.f - 2.f / (1.f + __expf(2.f * u));   // tanh(u)
    return 0.5f * x * (1.f + t);
}

__device__ __forceinline__ void split1(float a, unsigned short& hi, unsigned short& lo) {
    unsigned u = __float_as_uint(a);
    unsigned r = (u + 0x7fffu + ((u >> 16) & 1u)) & 0xffff0000u;
    hi = (unsigned short)(r >> 16);
    float al = a - __uint_as_float(r);
    unsigned u2 = __float_as_uint(al);
    lo = (unsigned short)((u2 + 0x7fffu + ((u2 >> 16) & 1u)) >> 16);
}

__device__ __forceinline__ void split8(const float* v, bf16x8& hi, bf16x8& lo) {
#pragma unroll
    for (int e = 0; e < 8; e++) {
        unsigned short h, l;
        split1(v[e], h, l);
        hi[e] = (short)h; lo[e] = (short)l;
    }
}

#define LMIN(da, pa, db, pb) { bool s_ = ((db) < (da)) || ((db) == (da) && (pb) < (pa)); \
                               (da) = s_ ? (db) : (da); (pa) = s_ ? (pb) : (pa); }

// ---------------------------------------------------------------- KNN: 4 waves x 512 pts local top-32, rank-merge
__global__ __launch_bounds__(256) void knn_kernel(const float* __restrict__ xyz, int* __restrict__ idx) {
    int bg = blockIdx.x;
    int b = bg >> 7, g = bg & 127;
    int t = threadIdx.x, w = t >> 6, lane = t & 63;
    const float* xb = xyz + (size_t)b * N_ * 3;
    float cx = xb[(g * 16) * 3 + 0], cy = xb[(g * 16) * 3 + 1], cz = xb[(g * 16) * 3 + 2];
    float d[8];
#pragma unroll
    for (int i = 0; i < 8; i++) {
        int p = w * 512 + i * 64 + lane;
        float dx = xb[p * 3 + 0] - cx, dy = xb[p * 3 + 1] - cy, dz = xb[p * 3 + 2] - cz;
        d[i] = dx * dx + dy * dy + dz * dz;
    }
    __shared__ float cd[128];
    __shared__ int   cpi[128];
    for (int r = 0; r < K_; r++) {
        float td[4]; int tp[4];
#pragma unroll
        for (int i = 0; i < 4; i++) {
            bool s = d[i + 4] < d[i];
            td[i] = s ? d[i + 4] : d[i];
            tp[i] = (s ? (i + 4) : i) * 64 + lane;
        }
        LMIN(td[0], tp[0], td[2], tp[2]);
        LMIN(td[1], tp[1], td[3], tp[3]);
        LMIN(td[0], tp[0], td[1], tp[1]);
        float bd = td[0]; int bp = tp[0];
#pragma unroll
        for (int off = 1; off < 64; off <<= 1) {
            float od = __shfl_xor(bd, off); int oq = __shfl_xor(bp, off);
            LMIN(bd, bp, od, oq);
        }
        if (lane == 0) { cd[w * 32 + r] = bd; cpi[w * 32 + r] = w * 512 + bp; }
        bool mine = ((bp & 63) == lane);
        int ki = bp >> 6;
#pragma unroll
        for (int i = 0; i < 8; i++) d[i] = (mine && ki == i) ? 1e38f : d[i];
    }
    __syncthreads();
    if (w == 0) {
        float a0 = cd[2 * lane], a1 = cd[2 * lane + 1];
        int p0 = cpi[2 * lane], p1 = cpi[2 * lane + 1];
        int r0 = 0, r1 = 0;
        for (int j = 0; j < 128; j++) {
            float dj = cd[j]; int pj = cpi[j];
            r0 += (dj < a0) || (dj == a0 && pj < p0);
            r1 += (dj < a1) || (dj == a1 && pj < p1);
        }
        int* op = idx + (size_t)bg * K_;
        if (r0 < K_) op[r0] = p0;
        if (r1 < K_) op[r1] = p1;
    }
}

// ---------------------------------------------------------------- group PointNet -> tokens (B,G,D)
__global__ __launch_bounds__(128) void tokens_kernel(const float* __restrict__ xyz, const int* __restrict__ idx,
                                                     const float* __restrict__ We1, const float* __restrict__ be1,
                                                     const float* __restrict__ We2, const float* __restrict__ be2,
                                                     float* __restrict__ tokens) {
    int bg = blockIdx.x;
    int b = bg >> 7, g = bg & 127;
    int t = threadIdx.x;
    __shared__ float rel[32][3];
    __shared__ float maxh[128];
    const float* xb = xyz + (size_t)b * N_ * 3;
    if (t < 32) {
        int p = idx[(size_t)bg * K_ + t];
        rel[t][0] = xb[p * 3 + 0] - xb[g * 16 * 3 + 0];
        rel[t][1] = xb[p * 3 + 1] - xb[g * 16 * 3 + 1];
        rel[t][2] = xb[p * 3 + 2] - xb[g * 16 * 3 + 2];
    }
    __syncthreads();
    float w0 = We1[t], w1 = We1[128 + t], w2 = We1[256 + t], bb = be1[t];
    float mx = -1e38f;
#pragma unroll 8
    for (int k = 0; k < 32; k++) {
        float v = rel[k][0] * w0 + rel[k][1] * w1 + rel[k][2] * w2 + bb;
        v = fmaxf(v, 0.f);
        mx = fmaxf(mx, v);
    }
    maxh[t] = mx;
    __syncthreads();
    float* tok = tokens + (size_t)bg * D_;
    for (int jj = t; jj < D_; jj += 128) {
        float acc = be2[jj];
        for (int c = 0; c < 128; c++) acc += maxh[c] * We2[c * D_ + jj];
        tok[jj] = acc;
    }
}

// ---------------------------------------------------------------- x = seq + type_emb + pos  (B,S,D)
__global__ __launch_bounds__(128) void buildx_kernel(const float* __restrict__ xyz, const float* __restrict__ tokens,
                                                     const float* __restrict__ Wp1, const float* __restrict__ bp1,
                                                     const float* __restrict__ Wp2, const float* __restrict__ bp2,
                                                     const float* __restrict__ bos, const float* __restrict__ eos,
                                                     const float* __restrict__ te, float* __restrict__ x) {
    int bs = blockIdx.x;
    int b = bs / S_, s = bs % S_;
    int t = threadIdx.x;
    __shared__ float h1[128];
    float c0 = 0.f, c1 = 0.f, c2 = 0.f;
    if (s >= 1 && s <= G_) {
        const float* xb = xyz + ((size_t)b * N_ + (size_t)(s - 1) * 16) * 3;
        c0 = xb[0]; c1 = xb[1]; c2 = xb[2];
    }
    h1[t] = fmaxf(c0 * Wp1[t] + c1 * Wp1[128 + t] + c2 * Wp1[256 + t] + bp1[t], 0.f);
    __syncthreads();
    int tid = (s == 0) ? 0 : ((s == S_ - 1) ? 2 : 1);
    float* xr = x + (size_t)bs * D_;
    for (int jj = t; jj < D_; jj += 128) {
        float acc = bp2[jj];
        for (int c = 0; c < 128; c++) acc += h1[c] * Wp2[c * D_ + jj];
        float base = (s == 0) ? bos[jj] : (s == S_ - 1 ? eos[jj] : tokens[((size_t)b * G_ + (s - 1)) * D_ + jj]);
        xr[jj] = base + te[tid * D_ + jj] + acc;
    }
}

// ---------------------------------------------------------------- LayerNorm (+ partial-sum reduce + pack)
__global__ __launch_bounds__(256) void ln_kernel(
    const float* __restrict__ xin, float* __restrict__ xout,
    const float* __restrict__ P0, const float* __restrict__ P1,
    const float* __restrict__ P2, const float* __restrict__ P3,
    const float* __restrict__ addb,
    const float* __restrict__ g, const float* __restrict__ b,
    unsigned short* __restrict__ pout, float* __restrict__ fout, int rows) {
    int r = blockIdx.x * 4 + (threadIdx.x >> 6);
    if (r >= rows) return;
    int lane = threadIdx.x & 63;
    const float* xr = xin + (size_t)r * 384;
    float v[6]; float s = 0.f, s2 = 0.f;
#pragma unroll
    for (int i = 0; i < 6; i++) {
        int c = lane + 64 * i;
        float t = xr[c];
        size_t o = (size_t)r * 384 + c;
        if (P0) t += P0[o] + P1[o];
        if (P2) t += P2[o] + P3[o];
        if (addb) t += addb[c];
        if (xout) xout[o] = t;
        v[i] = t; s += t; s2 += t * t;
    }
#pragma unroll
    for (int off = 1; off < 64; off <<= 1) { s += __shfl_xor(s, off); s2 += __shfl_xor(s2, off); }
    float m = s * (1.f / 384.f);
    float var = s2 * (1.f / 384.f) - m * m;
    float rstd = 1.0f / sqrtf(var + 1e-5f);
    int rl = r & 15, mfo = r >> 4;
#pragma unroll
    for (int i = 0; i < 6; i++) {
        int c = lane + 64 * i;
        float y = (v[i] - m) * rstd * g[c] + b[c];
        if (fout) fout[(size_t)r * 384 + c] = y;
        if (pout) {
            unsigned short hi, lo;
            split1(y, hi, lo);
            size_t ix = (((size_t)mfo * 12 + (c >> 5)) * 64 + rl + ((c >> 3) & 3) * 16) * 8 + (c & 7);
            pout[ix] = hi;
            pout[ix + 798720] = lo;
        }
    }
}

// ---------------------------------------------------------------- pack ALL weights in one launch
__global__ __launch_bounds__(256) void packall_kernel(
    const float* __restrict__ Wqkv, const float* __restrict__ Wo, const float* __restrict__ Wf1,
    const float* __restrict__ Wf2, const float* __restrict__ Wc1, const float* __restrict__ Wc2,
    const float* __restrict__ Wc3,
    unsigned short* __restrict__ qkvP, unsigned short* __restrict__ woP, unsigned short* __restrict__ f1P,
    unsigned short* __restrict__ f2P, unsigned short* __restrict__ wc1P, unsigned short* __restrict__ wc2P,
    unsigned short* __restrict__ wc3P) {
    int id = blockIdx.x;
    const float* src; unsigned short* dst; int Ksz, Nsz, nftot, kb, nxb, loc;
    if (id < 2592)       { loc = id;         src = Wqkv; dst = qkvP; Ksz = 384;  Nsz = 1152; nftot = 72; kb = 12; nxb = 18; }
    else if (id < 3456)  { loc = id - 2592;  src = Wo;   dst = woP;  Ksz = 384;  Nsz = 384;  nftot = 24; kb = 12; nxb = 6;  }
    else if (id < 6912)  { loc = id - 3456;  src = Wf1;  dst = f1P;  Ksz = 384;  Nsz = 1536; nftot = 96; kb = 12; nxb = 24; }
    else if (id < 10368) { loc = id - 6912;  src = Wf2;  dst = f2P;  Ksz = 1536; Nsz = 384;  nftot = 24; kb = 48; nxb = 6;  }
    else if (id < 10464) { loc = id - 10368; src = Wc1;  dst = wc1P; Ksz = 384;  Nsz = 512;  nftot = 32; kb = 12; nxb = 8;  }
    else if (id < 10528) { loc = id - 10464; src = Wc2;  dst = wc2P; Ksz = 512;  Nsz = 256;  nftot = 16; kb = 16; nxb = 4;  }
    else                 { loc = id - 10528; src = Wc3;  dst = wc3P; Ksz = 256;  Nsz = 50;   nftot = 4;  kb = 8;  nxb = 1;  }
    int xb = loc % nxb; int rest = loc / nxb; int kblk = rest % kb; int l = rest / kb;
    src += (size_t)l * Ksz * Nsz;
    dst += (size_t)l * 2 * nftot * kb * 512;
    int nf = xb * 4 + (threadIdx.x >> 6);
    if (nf >= nftot) return;
    int lane = threadIdx.x & 63;
    int n = nf * 16 + (lane & 15);
    int k0 = kblk * 32 + (lane >> 4) * 8;
    float av[8];
#pragma unroll
    for (int j = 0; j < 8; j++)
        av[j] = (n < Nsz) ? src[(size_t)(k0 + j) * Nsz + n] : 0.f;
    bf16x8 hi, lo;
    split8(av, hi, lo);
    size_t slot = ((size_t)nf * kb + kblk) * 512 + lane * 8;
    *(bf16x8*)(dst + slot) = hi;
    *(bf16x8*)(dst + slot + (size_t)nftot * kb * 512) = lo;
}

// ---------------------------------------------------------------- packed-A × packed-B MFMA GEMM
template<int MF, int NF, int WNS, int ACT, int FRAGOUT>
__global__ __launch_bounds__(WNS * 64) void gemm_pk(
    const unsigned short* __restrict__ Ap, const unsigned short* __restrict__ Bp,
    int mftot, int nftot, int kbt, int kbc,
    const float* __restrict__ bias, const float* __restrict__ bng, const float* __restrict__ bnb,
    float* __restrict__ C, unsigned short* __restrict__ Cp, size_t CploS, int ckbt,
    int M, int N) {
    int w = threadIdx.x >> 6, lane = threadIdx.x & 63;
    int mf0 = blockIdx.y * MF;
    int nf0 = (blockIdx.x * WNS + w) * NF;
    int k0 = blockIdx.z * kbc;
    f32x4 acc[MF][NF];
#pragma unroll
    for (int i = 0; i < MF; i++)
#pragma unroll
        for (int j = 0; j < NF; j++) acc[i][j] = (f32x4){0.f, 0.f, 0.f, 0.f};
    const size_t AloS = (size_t)mftot * kbt * 512, BloS = (size_t)nftot * kbt * 512;
    const unsigned short* Ab = Ap + ((size_t)mf0 * kbt + k0) * 512 + lane * 8;
    const unsigned short* Bb = Bp + ((size_t)nf0 * kbt + k0) * 512 + lane * 8;
#pragma unroll 2
    for (int kk = 0; kk < kbc; kk++) {
        bf16x8 ah[MF], al[MF], bh[NF], bl[NF];
#pragma unroll
        for (int i = 0; i < MF; i++) {
            const unsigned short* p = Ab + ((size_t)i * kbt + kk) * 512;
            ah[i] = *(const bf16x8*)p;
            al[i] = *(const bf16x8*)(p + AloS);
        }
#pragma unroll
        for (int j = 0; j < NF; j++) {
            const unsigned short* p = Bb + ((size_t)j * kbt + kk) * 512;
            bh[j] = *(const bf16x8*)p;
            bl[j] = *(const bf16x8*)(p + BloS);
        }
#pragma unroll
        for (int j = 0; j < NF; j++)
#pragma unroll
            for (int i = 0; i < MF; i++) {
                acc[i][j] = __builtin_amdgcn_mfma_f32_16x16x32_bf16(ah[i], bh[j], acc[i][j], 0, 0, 0);
                acc[i][j] = __builtin_amdgcn_mfma_f32_16x16x32_bf16(al[i], bh[j], acc[i][j], 0, 0, 0);
                acc[i][j] = __builtin_amdgcn_mfma_f32_16x16x32_bf16(ah[i], bl[j], acc[i][j], 0, 0, 0);
            }
    }
    int lm = lane & 15, lg = lane >> 4;
    const float rsq = 1.0f / sqrtf(1.0f + 1e-5f);
    float* Cz = C ? (C + (size_t)blockIdx.z * ((size_t)M * N)) : nullptr;
#pragma unroll
    for (int i = 0; i < MF; i++) {
#pragma unroll
        for (int r = 0; r < 4; r++) {
            int row = (mf0 + i) * 16 + lg * 4 + r;
#pragma unroll
            for (int j = 0; j < NF; j++) {
                int col = (nf0 + j) * 16 + lm;
                float v = acc[i][j][r];
                if (bias) v += bias[col];
                if (ACT == 2) v = gelu_f(v);
                else if (ACT == 3) v = fmaxf(bng[col] * v * rsq + bnb[col], 0.f);
                if (FRAGOUT) {
                    unsigned short hi, lo;
                    split1(v, hi, lo);
                    size_t ix = (((size_t)(mf0 + i) * ckbt + (col >> 5)) * 64 + (row & 15) + ((col >> 3) & 3) * 16) * 8 + (col & 7);
                    Cp[ix] = hi;
                    Cp[ix + CploS] = lo;
                } else if (col < N) {
                    Cz[(size_t)row * N + col] = v;
                }
            }
        }
    }
}

// ---------------------------------------------------------------- MFMA attention (swapped S^T = K·Q^T)
// Block = 4 independent waves; wave w owns q-rows [qc*48+w*16, +16). Grid = B*H*3.
// K staged as A-frags, V as B-frags (bf16 hi/lo) in LDS; softmax in-register per q-column;
// P redistributed C-layout -> A-layout via shfl; O = P·V via MFMA; 1/l folded into O-scale.
__global__ __launch_bounds__(256) void attn_kernel(const float* __restrict__ Q0,
                                                   unsigned short* __restrict__ outP, float* __restrict__ outF) {
    __shared__ unsigned short lds[38912];       // 77,824 B
    unsigned short* KPh = lds;                  // 9 fr x 2 kb x 512
    unsigned short* KPl = lds + 9216;
    unsigned short* VPh = lds + 18432;          // 4 df x 5 kb x 512
    unsigned short* VPl = lds + 28672;
    int blk = blockIdx.x;
    int bh = blk / 3, qc = blk % 3;
    int b = bh / H_, h = bh % H_;
    int t = threadIdx.x, w = t >> 6, lane = t & 63;
    int lm = lane & 15, lg = lane >> 4;
    const float* qkv = Q0 + (size_t)b * S_ * 1152;

    // stage K (rows=k, elems=d) as A-frags
    for (int u = t; u < 1152; u += 256) {
        int ln = u & 63;
        int row = (u >> 7) * 16 + (ln & 15);
        float av[8] = {0.f, 0.f, 0.f, 0.f, 0.f, 0.f, 0.f, 0.f};
        if (row < S_) {
            const float* p = qkv + (size_t)row * 1152 + 384 + h * 64 + ((u >> 6) & 1) * 32 + (ln >> 4) * 8;
            float4 x0 = *(const float4*)p, x1 = *(const float4*)(p + 4);
            av[0] = x0.x; av[1] = x0.y; av[2] = x0.z; av[3] = x0.w;
            av[4] = x1.x; av[5] = x1.y; av[6] = x1.z; av[7] = x1.w;
        }
        bf16x8 hi, lo; split8(av, hi, lo);
        *(bf16x8*)(KPh + u * 8) = hi;
        *(bf16x8*)(KPl + u * 8) = lo;
    }
    // stage V (elems=k, cols=d) as B-frags
    for (int u = t; u < 1280; u += 256) {
        int ln = u & 63;
        int col = 768 + h * 64 + (u / 320) * 16 + (ln & 15);
        int r0 = ((u / 64) % 5) * 32 + ((ln >> 4) << 3);
        float av[8];
#pragma unroll
        for (int e = 0; e < 8; e++) {
            int rr = r0 + e;
            av[e] = (rr < S_) ? qkv[(size_t)rr * 1152 + col] : 0.f;
        }
        bf16x8 hi, lo; split8(av, hi, lo);
        *(bf16x8*)(VPh + u * 8) = hi;
        *(bf16x8*)(VPl + u * 8) = lo;
    }
    __syncthreads();

    int qbase = qc * 48 + w * 16;
    // Q as B-frags (cols=q, elems=d), private per wave
    bf16x8 qh[2], ql[2];
#pragma unroll
    for (int kb = 0; kb < 2; kb++) {
        float av[8] = {0.f, 0.f, 0.f, 0.f, 0.f, 0.f, 0.f, 0.f};
        int row = qbase + lm;
        if (row < S_) {
            const float* p = qkv + (size_t)row * 1152 + h * 64 + kb * 32 + lg * 8;
            float4 x0 = *(const float4*)p, x1 = *(const float4*)(p + 4);
            av[0] = x0.x; av[1] = x0.y; av[2] = x0.z; av[3] = x0.w;
            av[4] = x1.x; av[5] = x1.y; av[6] = x1.z; av[7] = x1.w;
        }
        split8(av, qh[kb], ql[kb]);
    }
    // S^T = K·Q^T  (rows=k, cols=q)
    f32x4 acc[9];
#pragma unroll
    for (int fr = 0; fr < 9; fr++) acc[fr] = (f32x4){0.f, 0.f, 0.f, 0.f};
#pragma unroll
    for (int kb = 0; kb < 2; kb++)
#pragma unroll
        for (int fr = 0; fr < 9; fr++) {
            bf16x8 kh = *(const bf16x8*)(KPh + ((fr * 2 + kb) * 64 + lane) * 8);
            bf16x8 kl = *(const bf16x8*)(KPl + ((fr * 2 + kb) * 64 + lane) * 8);
            acc[fr] = __builtin_amdgcn_mfma_f32_16x16x32_bf16(kh, qh[kb], acc[fr], 0, 0, 0);
            acc[fr] = __builtin_amdgcn_mfma_f32_16x16x32_bf16(kl, qh[kb], acc[fr], 0, 0, 0);
            acc[fr] = __builtin_amdgcn_mfma_f32_16x16x32_bf16(kh, ql[kb], acc[fr], 0, 0, 0);
        }
    // scale + mask + softmax over k for q = lm
    float mx = -1e30f;
#pragma unroll
    for (int fr = 0; fr < 9; fr++)
#pragma unroll
        for (int r = 0; r < 4; r++) {
            int k = fr * 16 + lg * 4 + r;
            float v = (k < S_) ? acc[fr][r] * 0.125f : -1e30f;
            acc[fr][r] = v;
            mx = fmaxf(mx, v);
        }
    mx = fmaxf(mx, __shfl_xor(mx, 16));
    mx = fmaxf(mx, __shfl_xor(mx, 32));
    float sum = 0.f;
#pragma unroll
    for (int fr = 0; fr < 9; fr++)
#pragma unroll
        for (int r = 0; r < 4; r++) {
            float e = __expf(acc[fr][r] - mx);
            acc[fr][r] = e;
            sum += e;
        }
    sum += __shfl_xor(sum, 16);
    sum += __shfl_xor(sum, 32);
    // pack unnormalized P (bf16 hi/lo, u32 pairs per fr)
    unsigned ph[9][2], pl[9][2];
#pragma unroll
    for (int fr = 0; fr < 9; fr++) {
        unsigned short h0, h1, h2, h3, l0, l1, l2, l3;
        split1(acc[fr][0], h0, l0); split1(acc[fr][1], h1, l1);
        split1(acc[fr][2], h2, l2); split1(acc[fr][3], h3, l3);
        ph[fr][0] = (unsigned)h0 | ((unsigned)h1 << 16);
        ph[fr][1] = (unsigned)h2 | ((unsigned)h3 << 16);
        pl[fr][0] = (unsigned)l0 | ((unsigned)l1 << 16);
        pl[fr][1] = (unsigned)l2 | ((unsigned)l3 << 16);
    }
    // PV: O = P·V ; P A-frag assembled via shfl (lane lm = q in both layouts)
    f32x4 acco[4];
#pragma unroll
    for (int df = 0; df < 4; df++) acco[df] = (f32x4){0.f, 0.f, 0.f, 0.f};
    int s0l = lm + ((lg & 1) << 5);
    int s1l = s0l + 16;
    int frSel = lg >> 1;
#pragma unroll
    for (int kb = 0; kb < 5; kb++) {
        int fr0 = 2 * kb;
        unsigned x0h = __shfl((int)ph[fr0][0], s0l), x1h = __shfl((int)ph[fr0][1], s0l);
        unsigned x2h = __shfl((int)ph[fr0][0], s1l), x3h = __shfl((int)ph[fr0][1], s1l);
        unsigned x0l = __shfl((int)pl[fr0][0], s0l), x1l = __shfl((int)pl[fr0][1], s0l);
        unsigned x2l = __shfl((int)pl[fr0][0], s1l), x3l = __shfl((int)pl[fr0][1], s1l);
        unsigned y0h = 0, y1h = 0, y2h = 0, y3h = 0, y0l = 0, y1l = 0, y2l = 0, y3l = 0;
        if (kb < 4) {
            int fr1 = fr0 + 1;
            y0h = __shfl((int)ph[fr1][0], s0l); y1h = __shfl((int)ph[fr1][1], s0l);
            y2h = __shfl((int)ph[fr1][0], s1l); y3h = __shfl((int)ph[fr1][1], s1l);
            y0l = __shfl((int)pl[fr1][0], s0l); y1l = __shfl((int)pl[fr1][1], s0l);
            y2l = __shfl((int)pl[fr1][0], s1l); y3l = __shfl((int)pl[fr1][1], s1l);
        }
        union { unsigned u[4]; bf16x8 v; } pah, pal;
        pah.u[0] = frSel ? y0h : x0h; pah.u[1] = frSel ? y1h : x1h;
        pah.u[2] = frSel ? y2h : x2h; pah.u[3] = frSel ? y3h : x3h;
        pal.u[0] = frSel ? y0l : x0l; pal.u[1] = frSel ? y1l : x1l;
        pal.u[2] = frSel ? y2l : x2l; pal.u[3] = frSel ? y3l : x3l;
#pragma unroll
        for (int df = 0; df < 4; df++) {
            bf16x8 vh = *(const bf16x8*)(VPh + ((df * 5 + kb) * 64 + lane) * 8);
            bf16x8 vl = *(const bf16x8*)(VPl + ((df * 5 + kb) * 64 + lane) * 8);
            acco[df] = __builtin_amdgcn_mfma_f32_16x16x32_bf16(pah.v, vh, acco[df], 0, 0, 0);
            acco[df] = __builtin_amdgcn_mfma_f32_16x16x32_bf16(pal.v, vh, acco[df], 0, 0, 0);
            acco[df] = __builtin_amdgcn_mfma_f32_16x16x32_bf16(pah.v, vl, acco[df], 0, 0, 0);
        }
    }
    // epilogue: scale by 1/l[q], store
    float inv[4];
#pragma unroll
    for (int r = 0; r < 4; r++)
        inv[r] = 1.f / __shfl(sum, lg * 4 + r);
#pragma unroll
    for (int df = 0; df < 4; df++)
#pragma unroll
        for (int r = 0; r < 4; r++) {
            int qg = qbase + lg * 4 + r;
            if (qg >= S_) continue;
            float o = acco[df][r] * inv[r];
            int row2 = b * S_ + qg;
            int col = h * 64 + df * 16 + lm;
            if (outP) {
                unsigned short hi, lo;
                split1(o, hi, lo);
                size_t ix = (((size_t)(row2 >> 4) * 12 + (col >> 5)) * 64 + (row2 & 15) + ((col >> 3) & 3) * 16) * 8 + (col & 7);
                outP[ix] = hi;
                outP[ix + 798720] = lo;
            } else {
                outF[(size_t)row2 * D_ + col] = o;
            }
        }
}

// ---------------------------------------------------------------- fused: global max over patches -> head base vector
__global__ __launch_bounds__(512) void gmaxbase_kernel(const float* __restrict__ hh, const int* __restrict__ cls,
                                                       const float* __restrict__ Wl, const float* __restrict__ bl,
                                                       const float* __restrict__ Wc1, const float* __restrict__ bc1,
                                                       float* __restrict__ baseb) {
    int b = blockIdx.x;
    int t = threadIdx.x;
    __shared__ float gm[384];
    __shared__ float clsf[64];
    if (t < 384) {
        float m = -1e38f;
        for (int g = 0; g < G_; g++) m = fmaxf(m, hh[((size_t)b * S_ + 1 + g) * D_ + t]);
        gm[t] = m;
    } else if (t >= 448) {
        int c = t - 448;
        clsf[c] = fmaxf(Wl[cls[b] * 64 + c] + bl[c], 0.f);
    }
    __syncthreads();
    int j = t;
    if (j < 512) {
        float acc = bc1[j];
        for (int c = 0; c < 384; c++) acc += gm[c] * Wc1[(size_t)(384 + c) * 512 + j];
        for (int c = 0; c < 64; c++) acc += clsf[c] * Wc1[(size_t)(768 + c) * 512 + j];
        baseb[b * 512 + j] = acc;
    }
}

// ---------------------------------------------------------------- nearest-center assignment per point
__global__ __launch_bounds__(256) void assign_kernel(const float* __restrict__ xyz, int* __restrict__ assign) {
    int b = blockIdx.x >> 3;
    int n = ((blockIdx.x & 7) << 8) + threadIdx.x;
    __shared__ float cs[G_ * 3];
    const float* xb = xyz + (size_t)b * N_ * 3;
    int t = threadIdx.x;
    if (t < G_) {
        cs[t * 3 + 0] = xb[t * 16 * 3 + 0];
        cs[t * 3 + 1] = xb[t * 16 * 3 + 1];
        cs[t * 3 + 2] = xb[t * 16 * 3 + 2];
    }
    __syncthreads();
    float px = xb[n * 3 + 0], py = xb[n * 3 + 1], pz = xb[n * 3 + 2];
    float bd = 1e38f; int bi = 0;
    for (int g = 0; g < G_; g++) {
        float dx = px - cs[g * 3 + 0], dy = py - cs[g * 3 + 1], dz = pz - cs[g * 3 + 2];
        float dd = dx * dx + dy * dy + dz * dz;
        if (dd < bd) { bd = dd; bi = g; }
    }
    assign[(size_t)b * N_ + n] = bi;
}

// ---------------------------------------------------------------- y1 = relu(bn1(...)), packed (main) or f32 (fallback)
__global__ __launch_bounds__(256) void y1_kernel(const float* __restrict__ xyz, const int* __restrict__ assign,
                                                 const float* __restrict__ pf0, const float* __restrict__ pf1,
                                                 const float* __restrict__ baseb,
                                                 const float* __restrict__ Wc1,
                                                 const float* __restrict__ bn1g, const float* __restrict__ bn1b,
                                                 unsigned short* __restrict__ outP, float* __restrict__ outF) {
    int f4 = blockIdx.x * 256 + threadIdx.x;
    int row = f4 >> 7;
    int j = (f4 & 127) << 2;
    int b = row >> 11;
    int a = assign[row];
    size_t po = ((size_t)b * S_ + 1 + a) * 512 + j;
    float4 pf = *(const float4*)(pf0 + po);
    if (pf1) {
        const float4 p2 = *(const float4*)(pf1 + po);
        pf.x += p2.x; pf.y += p2.y; pf.z += p2.z; pf.w += p2.w;
    }
    const float4 bs = *(const float4*)(baseb + (size_t)b * 512 + j);
    const float* xp = xyz + (size_t)row * 3;
    float x0 = xp[0], x1 = xp[1], x2 = xp[2];
    const float4 w0 = *(const float4*)(Wc1 + (size_t)832 * 512 + j);
    const float4 w1 = *(const float4*)(Wc1 + (size_t)833 * 512 + j);
    const float4 w2 = *(const float4*)(Wc1 + (size_t)834 * 512 + j);
    const float4 g4 = *(const float4*)(bn1g + j);
    const float4 b4 = *(const float4*)(bn1b + j);
    float rs = 1.0f / sqrtf(1.0f + 1e-5f);
    float o0 = fmaxf(g4.x * rs * (pf.x + bs.x + x0 * w0.x + x1 * w1.x + x2 * w2.x) + b4.x, 0.f);
    float o1 = fmaxf(g4.y * rs * (pf.y + bs.y + x0 * w0.y + x1 * w1.y + x2 * w2.y) + b4.y, 0.f);
    float o2 = fmaxf(g4.z * rs * (pf.z + bs.z + x0 * w0.z + x1 * w1.z + x2 * w2.z) + b4.z, 0.f);
    float o3 = fmaxf(g4.w * rs * (pf.w + bs.w + x0 * w0.w + x1 * w1.w + x2 * w2.w) + b4.w, 0.f);
    if (outP) {
        unsigned short h0, h1, h2, h3, l0, l1, l2, l3;
        split1(o0, h0, l0); split1(o1, h1, l1); split1(o2, h2, l2); split1(o3, h3, l3);
        size_t ix = (((size_t)(row >> 4) * 16 + (j >> 5)) * 64 + (row & 15) + ((j >> 3) & 3) * 16) * 8 + (j & 7);
        *(uint2*)(outP + ix) = make_uint2((unsigned)h0 | ((unsigned)h1 << 16), (unsigned)h2 | ((unsigned)h3 << 16));
        *(uint2*)(outP + ix + 16777216) = make_uint2((unsigned)l0 | ((unsigned)l1 << 16), (unsigned)l2 | ((unsigned)l3 << 16));
    } else {
        *(float4*)(outF + (size_t)row * 512 + j) = make_float4(o0, o1, o2, o3);
    }
}

// ---------------------------------------------------------------- legacy fp32 GEMMs (fallback path)
__global__ __launch_bounds__(256) void gemm64_kernel(const float* __restrict__ A, const float* __restrict__ W,
                                                     const float* __restrict__ bias, const float* __restrict__ resid,
                                                     const float* __restrict__ bng, const float* __restrict__ bnb,
                                                     float* __restrict__ C, int M, int N, int K, int act) {
    __shared__ float As[16][68];
    __shared__ float Bs[16][68];
    int t = threadIdx.x;
    int tx = t & 15, ty = t >> 4;
    int m0 = blockIdx.y * 64, n0 = blockIdx.x * 64;
    int am = t >> 2, aseg = t & 3;
    int brow = t >> 4, bc4 = (t & 15) * 4;
    float acc[4][4] = {};
    int arow = m0 + am;
    bool av_ok = arow < M;
    const float* Ap = A + (size_t)arow * K + aseg * 4;
    for (int k0 = 0; k0 < K; k0 += 16) {
        float4 av = make_float4(0.f, 0.f, 0.f, 0.f);
        if (av_ok) av = *(const float4*)(Ap + k0);
        float4 bv;
        int bcol = n0 + bc4;
        const float* Wp = W + (size_t)(k0 + brow) * N + bcol;
        if (((N & 3) == 0) && (bcol + 3 < N)) bv = *(const float4*)Wp;
        else bv = make_float4(bcol + 0 < N ? Wp[0] : 0.f, bcol + 1 < N ? Wp[1] : 0.f,
                              bcol + 2 < N ? Wp[2] : 0.f, bcol + 3 < N ? Wp[3] : 0.f);
        __syncthreads();
        As[aseg * 4 + 0][am] = av.x; As[aseg * 4 + 1][am] = av.y;
        As[aseg * 4 + 2][am] = av.z; As[aseg * 4 + 3][am] = av.w;
        *(float4*)&Bs[brow][bc4] = bv;
        __syncthreads();
#pragma unroll
        for (int kk = 0; kk < 16; kk++) {
            float4 a = *(const float4*)&As[kk][ty * 4];
            float4 bq = *(const float4*)&Bs[kk][tx * 4];
            float ar[4] = {a.x, a.y, a.z, a.w};
            float br[4] = {bq.x, bq.y, bq.z, bq.w};
#pragma unroll
            for (int i = 0; i < 4; i++)
#pragma unroll
                for (int j = 0; j < 4; j++) acc[i][j] += ar[i] * br[j];
        }
    }
    float rs = 1.0f / sqrtf(1.0f + 1e-5f);
#pragma unroll
    for (int i = 0; i < 4; i++) {
        int row = m0 + ty * 4 + i;
        if (row >= M) continue;
#pragma unroll
        for (int j = 0; j < 4; j++) {
            int col = n0 + tx * 4 + j;
            if (col >= N) continue;
            float v = acc[i][j];
            if (bias) v += bias[col];
            if (act == 1) v = fmaxf(v, 0.f);
            else if (act == 2) v = gelu_f(v);
            else if (act == 3) v = fmaxf(bng[col] * v * rs + bnb[col], 0.f);
            if (resid) v += resid[(size_t)row * N + col];
            C[(size_t)row * N + col] = v;
        }
    }
}

__global__ __launch_bounds__(256) void gemm128_kernel(const float* __restrict__ A, const float* __restrict__ W,
                                                      const float* __restrict__ bias,
                                                      const float* __restrict__ bng, const float* __restrict__ bnb,
                                                      float* __restrict__ C, int M, int N, int K, int act) {
    __shared__ float As[16][132];
    __shared__ float Bs[16][132];
    int t = threadIdx.x;
    int tx = t & 15, ty = t >> 4;
    int m0 = blockIdx.y * 128, n0 = blockIdx.x * 128;
    float acc[8][8] = {};
    int am = t >> 1, aseg = (t & 1) * 8;
    int brow = t >> 4, bc4 = (t & 15) * 4;
    int arow = m0 + am;
    bool av_ok = arow < M;
    const float* Ap = A + (size_t)arow * K + aseg;
    for (int k0 = 0; k0 < K; k0 += 16) {
        float4 a0 = make_float4(0.f, 0.f, 0.f, 0.f), a1 = a0;
        if (av_ok) { a0 = *(const float4*)(Ap + k0); a1 = *(const float4*)(Ap + k0 + 4); }
        const float* Wp = W + (size_t)(k0 + brow) * N + n0;
        float4 b0 = *(const float4*)(Wp + bc4);
        float4 b1 = *(const float4*)(Wp + bc4 + 64);
        __syncthreads();
        As[aseg + 0][am] = a0.x; As[aseg + 1][am] = a0.y; As[aseg + 2][am] = a0.z; As[aseg + 3][am] = a0.w;
        As[aseg + 4][am] = a1.x; As[aseg + 5][am] = a1.y; As[aseg + 6][am] = a1.z; As[aseg + 7][am] = a1.w;
        *(float4*)&Bs[brow][bc4] = b0;
        *(float4*)&Bs[brow][bc4 + 64] = b1;
        __syncthreads();
#pragma unroll
        for (int kk = 0; kk < 16; kk++) {
            float4 a0r = *(const float4*)&As[kk][ty * 4];
            float4 a1r = *(const float4*)&As[kk][ty * 4 + 64];
            float4 b0r = *(const float4*)&Bs[kk][tx * 4];
            float4 b1r = *(const float4*)&Bs[kk][tx * 4 + 64];
            float ar[8] = {a0r.x, a0r.y, a0r.z, a0r.w, a1r.x, a1r.y, a1r.z, a1r.w};
            float br[8] = {b0r.x, b0r.y, b0r.z, b0r.w, b1r.x, b1r.y, b1r.z, b1r.w};
#pragma unroll
            for (int i = 0; i < 8; i++)
#pragma unroll
                for (int j = 0; j < 8; j++) acc[i][j] += ar[i] * br[j];
        }
    }
    float rs = 1.0f / sqrtf(1.0f + 1e-5f);
#pragma unroll
    for (int i = 0; i < 8; i++) {
        int row = m0 + ((i < 4) ? (ty * 4 + i) : (ty * 4 + 64 + (i - 4)));
        if (row >= M) continue;
#pragma unroll
        for (int j = 0; j < 8; j++) {
            int col = n0 + ((j < 4) ? (tx * 4 + j) : (tx * 4 + 64 + (j - 4)));
            if (col >= N) continue;
            float v = acc[i][j];
            if (bias) v += bias[col];
            if (act == 3) v = fmaxf(bng[col] * v * rs + bnb[col], 0.f);
            else if (act == 1) v = fmaxf(v, 0.f);
            C[(size_t)row * N + col] = v;
        }
    }
}

// ---------------------------------------------------------------- host
extern "C" void kernel_launch(void* const* d_in, const int* in_sizes, int n_in,
                              void* d_out, int out_size, void* d_ws, size_t ws_size,
                              hipStream_t stream) {
    (void)in_sizes; (void)n_in; (void)out_size;
    const float* xyz    = (const float*)d_in[0];
    const int*   cls    = (const int*)d_in[1];
    const float* We1    = (const float*)d_in[2];
    const float* be1    = (const float*)d_in[3];
    const float* We2    = (const float*)d_in[4];
    const float* be2    = (const float*)d_in[5];
    const float* Wp1    = (const float*)d_in[6];
    const float* bp1    = (const float*)d_in[7];
    const float* Wp2    = (const float*)d_in[8];
    const float* bp2    = (const float*)d_in[9];
    const float* bos    = (const float*)d_in[10];
    const float* eos    = (const float*)d_in[11];
    const float* te     = (const float*)d_in[12];
    const float* ln1_g  = (const float*)d_in[13];
    const float* ln1_b  = (const float*)d_in[14];
    const float* Wqkv   = (const float*)d_in[15];
    const float* bqkv   = (const float*)d_in[16];
    const float* Wo     = (const float*)d_in[17];
    const float* bo     = (const float*)d_in[18];
    const float* ln2_g  = (const float*)d_in[19];
    const float* ln2_b  = (const float*)d_in[20];
    const float* Wf1    = (const float*)d_in[21];
    const float* bf1    = (const float*)d_in[22];
    const float* Wf2    = (const float*)d_in[23];
    const float* bf2    = (const float*)d_in[24];
    const float* lnf_g  = (const float*)d_in[25];
    const float* lnf_b  = (const float*)d_in[26];
    const float* Wl     = (const float*)d_in[27];
    const float* bl     = (const float*)d_in[28];
    const float* Wc1    = (const float*)d_in[29];
    const float* bc1    = (const float*)d_in[30];
    const float* bn1_g  = (const float*)d_in[31];
    const float* bn1_b  = (const float*)d_in[32];
    const float* Wc2    = (const float*)d_in[33];
    const float* bc2    = (const float*)d_in[34];
    const float* bn2_g  = (const float*)d_in[35];
    const float* bn2_b  = (const float*)d_in[36];
    const float* Wc3    = (const float*)d_in[37];
    const float* bc3    = (const float*)d_in[38];
    float* out = (float*)d_out;

    float* ws = (float*)d_ws;
    size_t off = 0;
    auto alloc = [&](size_t nf) { float* p = ws + off; off += nf; return p; };
    float* x      = alloc((size_t)2080 * 384);
    float* hh     = alloc((size_t)2080 * 384);
    float* baseb  = alloc(16 * 512);
    int*   idx    = (int*)alloc((size_t)2048 * 32);
    int*   assign = (int*)alloc(32768);
    unsigned short* hhP = (unsigned short*)alloc(798720);
    float* regionB = alloc(9584640);
    float* y1R    = alloc((size_t)16777216);      // y1 packed planes (or f32 fallback); also tokens pre-phase
    unsigned short* qkvP = (unsigned short*)alloc(5308416);
    unsigned short* woP  = (unsigned short*)alloc(1769472);
    unsigned short* f1P  = (unsigned short*)alloc(7077888);
    unsigned short* f2P  = (unsigned short*)alloc(7077888);
    unsigned short* wc1P = (unsigned short*)alloc(196608);
    unsigned short* wc2P = (unsigned short*)alloc(131072);
    unsigned short* wc3P = (unsigned short*)alloc(16384);
    size_t need_bytes = off * 4;

    float* tokens = y1R;
    unsigned short* y1P = (unsigned short*)y1R;
    const size_t FS = (size_t)2080 * 384;        // proj/f2 partial stride
    unsigned short* hidP = (unsigned short*)regionB;
    float* f2Pt = regionB + 3194880;             // f2 partials (4 slots)
    unsigned short* y2P = (unsigned short*)regionB;
    const size_t PFS = (size_t)2080 * 512;       // pfp partial stride

    if (ws_size >= need_bytes) {
        packall_kernel<<<dim3(10536), 256, 0, stream>>>(Wqkv, Wo, Wf1, Wf2, Wc1, Wc2, Wc3,
                                                        qkvP, woP, f1P, f2P, wc1P, wc2P, wc3P);
        knn_kernel<<<dim3(2048), dim3(256), 0, stream>>>(xyz, idx);
        tokens_kernel<<<dim3(2048), dim3(128), 0, stream>>>(xyz, idx, We1, be1, We2, be2, tokens);
        buildx_kernel<<<dim3(2080), dim3(128), 0, stream>>>(xyz, tokens, Wp1, bp1, Wp2, bp2, bos, eos, te, x);

        for (int l = 0; l < L_; l++) {
            if (l == 0)
                ln_kernel<<<dim3(520), dim3(256), 0, stream>>>(x, nullptr, nullptr, nullptr, nullptr, nullptr,
                                                               nullptr, ln1_g, ln1_b, hhP, nullptr, 2080);
            else
                ln_kernel<<<dim3(520), dim3(256), 0, stream>>>(x, x, f2Pt, f2Pt + FS, f2Pt + 2 * FS, f2Pt + 3 * FS,
                                                               bf2 + (l - 1) * 384, ln1_g + l * 384, ln1_b + l * 384,
                                                               hhP, nullptr, 2080);
            gemm_pk<2, 2, 2, 0, 0><<<dim3(18, 65, 1), dim3(128), 0, stream>>>(
                hhP, qkvP + (size_t)l * 884736, 130, 72, 12, 12, bqkv + l * 1152, nullptr, nullptr,
                regionB, nullptr, 0, 0, 2080, 1152);
            attn_kernel<<<dim3(288), dim3(256), 0, stream>>>(regionB, hhP, nullptr);
            gemm_pk<2, 2, 2, 0, 0><<<dim3(6, 65, 4), dim3(128), 0, stream>>>(
                hhP, woP + (size_t)l * 294912, 130, 24, 12, 3, nullptr, nullptr, nullptr,
                regionB, nullptr, 0, 0, 2080, 384);
            ln_kernel<<<dim3(520), dim3(256), 0, stream>>>(x, x, regionB, regionB + FS, regionB + 2 * FS, regionB + 3 * FS,
                                                           bo + l * 384, ln2_g + l * 384, ln2_b + l * 384,
                                                           hhP, nullptr, 2080);
            gemm_pk<2, 2, 2, 2, 1><<<dim3(24, 65, 1), dim3(128), 0, stream>>>(
                hhP, f1P + (size_t)l * 1179648, 130, 96, 12, 12, bf1 + l * 1536, nullptr, nullptr,
                nullptr, hidP, 3194880, 48, 2080, 1536);
            gemm_pk<2, 2, 2, 0, 0><<<dim3(6, 65, 4), dim3(128), 0, stream>>>(
                hidP, f2P + (size_t)l * 1179648, 130, 24, 48, 12, nullptr, nullptr, nullptr,
                f2Pt, nullptr, 0, 0, 2080, 384);
        }

        ln_kernel<<<dim3(520), dim3(256), 0, stream>>>(x, nullptr, f2Pt, f2Pt + FS, f2Pt + 2 * FS, f2Pt + 3 * FS,
                                                       bf2 + 11 * 384, lnf_g, lnf_b, hhP, hh, 2080);
        gmaxbase_kernel<<<dim3(16), dim3(512), 0, stream>>>(hh, cls, Wl, bl, Wc1, bc1, baseb);
        gemm_pk<2, 2, 2, 0, 0><<<dim3(8, 65, 2), dim3(128), 0, stream>>>(
            hhP, wc1P, 130, 32, 12, 6, nullptr, nullptr, nullptr, regionB, nullptr, 0, 0, 2080, 512);
        assign_kernel<<<dim3(128), dim3(256), 0, stream>>>(xyz, assign);
        y1_kernel<<<dim3(16384), dim3(256), 0, stream>>>(xyz, assign, regionB, regionB + PFS,
                                                         baseb, Wc1, bn1_g, bn1_b, y1P, nullptr);
        gemm_pk<2, 4, 4, 3, 1><<<dim3(1, 1024, 1), dim3(256), 0, stream>>>(
            y1P, wc2P, 2048, 16, 16, 16, bc2, bn2_g, bn2_b, nullptr, y2P, 8388608, 8, 32768, 256);
        gemm_pk<2, 1, 4, 0, 0><<<dim3(1, 1024, 1), dim3(256), 0, stream>>>(
            y2P, wc3P, 2048, 4, 8, 8, bc3, nullptr, nullptr, out, nullptr, 0, 0, 32768, 50);
    } else {
        // -------- fallback: fp32 path --------
        float* qkvb = regionB;
        float* obuf = regionB + (size_t)2080 * 1152;
        float* hid  = regionB;
        float* pfp  = regionB;
        float* y2f  = regionB;
        float* y1f  = y1R;
        knn_kernel<<<dim3(2048), dim3(256), 0, stream>>>(xyz, idx);
        tokens_kernel<<<dim3(2048), dim3(128), 0, stream>>>(xyz, idx, We1, be1, We2, be2, tokens);
        buildx_kernel<<<dim3(2080), dim3(128), 0, stream>>>(xyz, tokens, Wp1, bp1, Wp2, bp2, bos, eos, te, x);
        for (int l = 0; l < L_; l++) {
            ln_kernel<<<dim3(520), dim3(256), 0, stream>>>(x, nullptr, nullptr, nullptr, nullptr, nullptr, nullptr,
                                                           ln1_g + l * 384, ln1_b + l * 384, nullptr, hh, 2080);
            gemm64_kernel<<<dim3(18, 33), dim3(256), 0, stream>>>(hh, Wqkv + (size_t)l * 384 * 1152, bqkv + l * 1152,
                                                                  nullptr, nullptr, nullptr, qkvb, 2080, 1152, 384, 0);
            attn_kernel<<<dim3(288), dim3(256), 0, stream>>>(qkvb, nullptr, obuf);
            gemm64_kernel<<<dim3(6, 33), dim3(256), 0, stream>>>(obuf, Wo + (size_t)l * 384 * 384, bo + l * 384,
                                                                 x, nullptr, nullptr, x, 2080, 384, 384, 0);
            ln_kernel<<<dim3(520), dim3(256), 0, stream>>>(x, nullptr, nullptr, nullptr, nullptr, nullptr, nullptr,
                                                           ln2_g + l * 384, ln2_b + l * 384, nullptr, hh, 2080);
            gemm64_kernel<<<dim3(24, 33), dim3(256), 0, stream>>>(hh, Wf1 + (size_t)l * 384 * 1536, bf1 + l * 1536,
                                                                  nullptr, nullptr, nullptr, hid, 2080, 1536, 384, 2);
            gemm64_kernel<<<dim3(6, 33), dim3(256), 0, stream>>>(hid, Wf2 + (size_t)l * 1536 * 384, bf2 + l * 384,
                                                                 x, nullptr, nullptr, x, 2080, 384, 1536, 0);
        }
        ln_kernel<<<dim3(520), dim3(256), 0, stream>>>(x, nullptr, nullptr, nullptr, nullptr, nullptr, nullptr,
                                                       lnf_g, lnf_b, nullptr, hh, 2080);
        gmaxbase_kernel<<<dim3(16), dim3(512), 0, stream>>>(hh, cls, Wl, bl, Wc1, bc1, baseb);
        gemm64_kernel<<<dim3(8, 33), dim3(256), 0, stream>>>(hh, Wc1, nullptr, nullptr, nullptr, nullptr,
                                                             pfp, 2080, 512, 384, 0);
        assign_kernel<<<dim3(128), dim3(256), 0, stream>>>(xyz, assign);
        y1_kernel<<<dim3(16384), dim3(256), 0, stream>>>(xyz, assign, pfp, nullptr, baseb, Wc1, bn1_g, bn1_b,
                                                         nullptr, y1f);
        gemm128_kernel<<<dim3(2, 256), dim3(256), 0, stream>>>(y1f, Wc2, bc2, bn2_g, bn2_b, y2f, 32768, 256, 512, 3);
        gemm64_kernel<<<dim3(1, 512), dim3(256), 0, stream>>>(y2f, Wc3, bc3, nullptr, nullptr, nullptr,
                                                              out, 32768, 50, 256, 0);
    }
}